// Round 12
// baseline (1692.587 us; speedup 1.0000x reference)
//
#include <hip/hip_runtime.h>

#define NV 262144          // 64^3

using bf16x8 = __attribute__((ext_vector_type(8))) short;
using f32x4  = __attribute__((ext_vector_type(4))) float;

static __device__ __forceinline__ unsigned short f2bf(float x) {
  unsigned int u = __float_as_uint(x);
  unsigned int r = (u + 0x7FFFu + ((u >> 16) & 1u)) >> 16;
  return (unsigned short)r;
}

// ---------------- Gaussian weights (13-tap, sigma=2) ----------------
static __device__ __forceinline__ void gauss_weights(float K[13]) {
  float s = 0.f;
#pragma unroll
  for (int j = 0; j < 13; ++j) {
    float r = (float)(j - 6);
    K[j] = expf(-0.125f * r * r);
    s += K[j];
  }
#pragma unroll
  for (int j = 0; j < 13; ++j) K[j] = K[j] / s;
}

// ---------------- trilinear helpers ----------------
static __device__ __forceinline__ void tl_make(float gx, float gy, float gz,
                                               int sx, int sy, int sz,
                                               int id[8], float wt[8]) {
  float x = fminf(fmaxf((gx + 1.0f) * 0.5f * 63.0f, 0.0f), 63.0f);
  float y = fminf(fmaxf((gy + 1.0f) * 0.5f * 63.0f, 0.0f), 63.0f);
  float z = fminf(fmaxf((gz + 1.0f) * 0.5f * 63.0f, 0.0f), 63.0f);
  float x0f = floorf(x), y0f = floorf(y), z0f = floorf(z);
  int x0 = (int)x0f, y0 = (int)y0f, z0 = (int)z0f;
  int x1 = min(x0 + 1, 63), y1 = min(y0 + 1, 63), z1 = min(z0 + 1, 63);
  float wx = x - x0f, wy = y - y0f, wz = z - z0f;
  float ux = 1.f - wx, uy = 1.f - wy, uz = 1.f - wz;
  int X0 = x0 * sx, X1 = x1 * sx, Y0 = y0 * sy, Y1 = y1 * sy, Z0 = z0 * sz, Z1 = z1 * sz;
  id[0] = Z0 + Y0 + X0; wt[0] = uz * uy * ux;
  id[1] = Z0 + Y0 + X1; wt[1] = uz * uy * wx;
  id[2] = Z0 + Y1 + X0; wt[2] = uz * wy * ux;
  id[3] = Z0 + Y1 + X1; wt[3] = uz * wy * wx;
  id[4] = Z1 + Y0 + X0; wt[4] = wz * uy * ux;
  id[5] = Z1 + Y0 + X1; wt[5] = wz * uy * wx;
  id[6] = Z1 + Y1 + X0; wt[6] = wz * wy * ux;
  id[7] = Z1 + Y1 + X1; wt[7] = wz * wy * wx;
}

static __device__ __forceinline__ float tl_apply(const float* __restrict__ img,
                                                 const int id[8], const float wt[8]) {
  float s = 0.f;
#pragma unroll
  for (int k = 0; k < 8; ++k) s = fmaf(wt[k], img[id[k]], s);
  return s;
}

// ---------------- init (also packs cin_b for conv1) ----------------
__global__ void init_kernel(const float* __restrict__ src, const float* __restrict__ tgt,
                            const float* __restrict__ z0,
                            float* __restrict__ residual, float* __restrict__ image,
                            float* __restrict__ rd0, float* __restrict__ phi0,
                            float* __restrict__ outRes0, unsigned short* __restrict__ cinb) {
  int idx = blockIdx.x * 256 + threadIdx.x;
  int d = idx >> 12, h = (idx >> 6) & 63, w = idx & 63;
  float z = z0[idx];
  float sv = src[idx];
  residual[idx] = z;
  outRes0[idx] = z;
  image[idx] = sv;
  rd0[idx] = 0.f;
  const float step = 2.0f / 63.0f;
  phi0[idx] = -1.f + w * step;
  phi0[NV + idx] = -1.f + h * step;
  phi0[2 * NV + idx] = -1.f + d * step;
  unsigned int u0 = (unsigned int)f2bf(z) | ((unsigned int)f2bf(sv) << 16);
  unsigned int u1 = (unsigned int)f2bf(tgt[idx]);
  *(uint2*)(cinb + (size_t)idx * 4) = make_uint2(u0, u1);
}

// ---------------- fused gradient + smooth-D pass (+ grads output at j==6) ----------------
__global__ void gsd_kernel(const float* __restrict__ img, const float* __restrict__ residual,
                           float* __restrict__ gout, float* __restrict__ t1) {
  int idx = blockIdx.x * 256 + threadIdx.x;
  int d = idx >> 12, h = (idx >> 6) & 63, w = idx & 63;
  float K[13]; gauss_weights(K);
  int wp = min(w + 1, 63), wm = max(w - 1, 0);
  int hp = min(h + 1, 63), hm = max(h - 1, 0);
  float a0 = 0.f, a1 = 0.f, a2 = 0.f;
#pragma unroll
  for (int j = 0; j < 13; ++j) {
    int dd = d + j - 6;
    if ((unsigned)dd < 64u) {
      int b = (dd << 12) + (h << 6);
      int dp = min(dd + 1, 63), dm = max(dd - 1, 0);
      float gx = 0.5f * (img[b + wp] - img[b + wm]);
      float gy = 0.5f * (img[(dd << 12) + (hp << 6) + w] - img[(dd << 12) + (hm << 6) + w]);
      float gz = 0.5f * (img[(dp << 12) + (h << 6) + w] - img[(dm << 12) + (h << 6) + w]);
      float r = residual[b + w];
      if (j == 6) {
        gout[idx] = gx; gout[NV + idx] = gy; gout[2 * NV + idx] = gz;
      }
      a0 = fmaf(K[j], -r * gx, a0);
      a1 = fmaf(K[j], -r * gy, a1);
      a2 = fmaf(K[j], -r * gz, a2);
    }
  }
  t1[idx] = a0; t1[NV + idx] = a1; t1[2 * NV + idx] = a2;
}

// ---------------- fused smooth-H + smooth-W + fields output ----------------
__global__ __launch_bounds__(256) void smooth_hw(const float* __restrict__ t1,
                                                 float* __restrict__ vbuf,
                                                 float* __restrict__ fout) {
  __shared__ float shin[16][64];
  __shared__ float shh[4][64];
  int w = threadIdx.x & 63;
  int ty = threadIdx.x >> 6;
  int h0 = blockIdx.x * 4;
  int d  = blockIdx.y;
  float K[13]; gauss_weights(K);
  for (int c = 0; c < 3; ++c) {
    __syncthreads();
    const float* tc = t1 + (size_t)c * NV + (d << 12);
    for (int r = ty; r < 16; r += 4) {
      int hh = h0 - 6 + r;
      shin[r][w] = ((unsigned)hh < 64u) ? tc[(hh << 6) + w] : 0.f;
    }
    __syncthreads();
    float acc = 0.f;
#pragma unroll
    for (int j = 0; j < 13; ++j) {
      int hh = h0 + ty + j - 6;
      if ((unsigned)hh < 64u) acc = fmaf(K[j], shin[ty + j][w], acc);
    }
    shh[ty][w] = acc;
    __syncthreads();
    float o = 0.f;
#pragma unroll
    for (int j = 0; j < 13; ++j) {
      int wj = w + j - 6;
      if ((unsigned)wj < 64u) o = fmaf(K[j], shh[ty][wj], o);
    }
    int h = h0 + ty;
    vbuf[(size_t)c * NV + (d << 12) + (h << 6) + w] = o;
    fout[((size_t)(w << 12) + (h << 6) + d) * 3 + c] = o;
  }
}

// ============ MFMA helpers, 512-thread tile 16x4x8 (halo 18x6x10), channel-last bf16 ============
// LDS per buffer: 1080 voxels x 32 B = 34560 B.
// addr(dd,hh,q,wws) = dd*3456 + hh*576 + q*288 + wws*16   (dd 0..9, hh 0..5, wws 0..17)
#define MFMA_PREPD(XB)                                                             \
  int gofs[5]; int lofs[5]; bool gok[5]; bool sval[5];                             \
  _Pragma("unroll")                                                                \
  for (int k = 0; k < 5; ++k) {                                                    \
    int s = tid + k * 512;                                                         \
    sval[k] = (s < 2160);                                                          \
    int hpos = s >> 1, q = s & 1;                                                  \
    int wws = hpos % 18; int rest = hpos / 18;                                     \
    int hh = rest % 6;   int dd = rest / 6;                                        \
    int gz = d0 + dd - 1, gy = h0 + hh - 1, gx = w0 + wws - 1;                     \
    bool ok = sval[k] && ((unsigned)gz < 64u) && ((unsigned)gy < 64u) && ((unsigned)gx < 64u); \
    gok[k] = ok;                                                                   \
    gofs[k] = ok ? ((((gz << 12) + (gy << 6) + gx) << 6) + q * 8) : 0;             \
    lofs[k] = dd * 3456 + hh * 576 + q * 288 + wws * 16;                           \
  }

#define MFMA_STAGED_TO(XB, G, DSTBUF)                                              \
  {                                                                                \
    uint4 stg[5];                                                                  \
    _Pragma("unroll")                                                              \
    for (int k = 0; k < 5; ++k)                                                    \
      stg[k] = gok[k] ? *(const uint4*)((XB) + gofs[k] + (G) * 16)                 \
                      : make_uint4(0u, 0u, 0u, 0u);                                \
    _Pragma("unroll")                                                              \
    for (int k = 0; k < 5; ++k)                                                    \
      if (sval[k]) *(uint4*)((DSTBUF) + lofs[k]) = stg[k];                         \
  }

#define TAP_ADDRD                                                                  \
  int tap = 2 * c + (kb >> 1);                                                     \
  int tapc = min(tap, 26);                                                         \
  int kd = (tapc * 57) >> 9;                                                       \
  int rem = tapc - kd * 9;                                                         \
  int kh = (rem * 43) >> 7;                                                        \
  int kw = rem - kh * 3;                                                           \
  int rb = kd * 3456 + kh * 576 + (kb & 1) * 288 + kw * 16;

// bijective XCD swizzle for 512-block grid (4,16,8): 64-chunk per XCD
#define MFMA_BLOCKIDD                                                              \
  int f = blockIdx.x + 4 * (blockIdx.y + 16 * blockIdx.z);                         \
  int nid = (f & 7) * 64 + (f >> 3);                                               \
  const int w0 = (nid & 3) * 16, h0 = ((nid >> 2) & 15) * 4, d0 = (nid >> 6) * 8;

// conv1 keeps the 16x4x4 mapping (grid 4,16,16; 128-chunk per XCD)
#define MFMA_BLOCKID4                                                              \
  int f = blockIdx.x + 4 * (blockIdx.y + 16 * blockIdx.z);                         \
  int nid = (f & 7) * 128 + (f >> 3);                                              \
  const int w0 = (nid & 3) * 16, h0 = ((nid >> 2) & 15) * 4, d0 = (nid >> 6) * 4;

// channel-last bf16 epilogue (m = mf*16 + kb*4 + r, n = ww)
#define MFMA_EPILOGUE(ACC, XOUT)                                                   \
  _Pragma("unroll")                                                                \
  for (int nf = 0; nf < 4; ++nf) {                                                 \
    int idx = ((d0 + wv) << 12) + ((h0 + nf) << 6) + (w0 + ww);                    \
    unsigned int base = (unsigned int)idx * 64u + kb * 4u;                         \
    _Pragma("unroll")                                                              \
    for (int mf = 0; mf < 4; ++mf) {                                               \
      float v0 = ACC[mf][nf][0], v1 = ACC[mf][nf][1];                              \
      float v2 = ACC[mf][nf][2], v3 = ACC[mf][nf][3];                              \
      v0 = (v0 >= 0.f) ? v0 : 0.01f * v0;                                          \
      v1 = (v1 >= 0.f) ? v1 : 0.01f * v1;                                          \
      v2 = (v2 >= 0.f) ? v2 : 0.01f * v2;                                          \
      v3 = (v3 >= 0.f) ? v3 : 0.01f * v3;                                          \
      unsigned int u0 = (unsigned int)f2bf(v0) | ((unsigned int)f2bf(v1) << 16);   \
      unsigned int u1 = (unsigned int)f2bf(v2) | ((unsigned int)f2bf(v3) << 16);   \
      *(uint2*)((XOUT) + base + mf * 16u) = make_uint2(u0, u1);                    \
    }                                                                              \
  }

// ---------------- conv1: MFMA implicit GEMM (3ch -> 50), K=128, tile 16x4x4 ----------------
__global__ __launch_bounds__(256) void conv1_mfma(const unsigned short* __restrict__ cinb,
                                                  const unsigned short* __restrict__ w1m,
                                                  unsigned short* __restrict__ x1b) {
  __shared__ char sh[1296 * 8];
  const int tid = threadIdx.x;
  const int lane = tid & 63;
  const int wv = tid >> 6;
  const int ww = lane & 15;
  const int kb = lane >> 4;
  MFMA_BLOCKID4

  int gofs[6]; int lofs[6]; bool gok[6]; bool sval[6];
#pragma unroll
  for (int k = 0; k < 6; ++k) {
    int s = tid + k * 256;
    sval[k] = (s < 1296);
    int wws = s % 18; int rest = s / 18;
    int hh = rest % 6; int dd = rest / 6;
    int gz = d0 + dd - 1, gy = h0 + hh - 1, gx = w0 + wws - 1;
    bool ok = sval[k] && ((unsigned)gz < 64u) && ((unsigned)gy < 64u) && ((unsigned)gx < 64u);
    gok[k] = ok;
    gofs[k] = ok ? (((gz << 12) + (gy << 6) + gx) * 4) : 0;
    lofs[k] = s * 8;
  }
  {
    uint2 stg[6];
#pragma unroll
    for (int k = 0; k < 6; ++k)
      stg[k] = gok[k] ? *(const uint2*)(cinb + gofs[k]) : make_uint2(0u, 0u);
#pragma unroll
    for (int k = 0; k < 6; ++k)
      if (sval[k]) *(uint2*)(sh + lofs[k]) = stg[k];
  }
  __syncthreads();

  f32x4 acc[4][4];
#pragma unroll
  for (int mf = 0; mf < 4; ++mf)
#pragma unroll
    for (int nf = 0; nf < 4; ++nf) acc[mf][nf] = (f32x4)0.f;

#pragma unroll
  for (int g = 0; g < 4; ++g) {
    bf16x8 a0 = *(const bf16x8*)(w1m + (((g * 4 + 0) * 64 + lane) << 3));
    bf16x8 a1 = *(const bf16x8*)(w1m + (((g * 4 + 1) * 64 + lane) << 3));
    bf16x8 a2 = *(const bf16x8*)(w1m + (((g * 4 + 2) * 64 + lane) << 3));
    bf16x8 a3 = *(const bf16x8*)(w1m + (((g * 4 + 3) * 64 + lane) << 3));
    int tap0 = 8 * g + 2 * kb;
    int t0 = min(tap0, 26), t1 = min(tap0 + 1, 26);
    int kd0 = (t0 * 57) >> 9; int r0 = t0 - kd0 * 9; int kh0 = (r0 * 43) >> 7; int kw0 = r0 - kh0 * 3;
    int kd1 = (t1 * 57) >> 9; int r1 = t1 - kd1 * 9; int kh1 = (r1 * 43) >> 7; int kw1 = r1 - kh1 * 3;
#pragma unroll
    for (int nf = 0; nf < 4; ++nf) {
      union { uint2 u[2]; bf16x8 v; } bb;
      bb.u[0] = *(const uint2*)(sh + (((wv + kd0) * 6 + (nf + kh0)) * 18 + (ww + kw0)) * 8);
      bb.u[1] = *(const uint2*)(sh + (((wv + kd1) * 6 + (nf + kh1)) * 18 + (ww + kw1)) * 8);
      acc[0][nf] = __builtin_amdgcn_mfma_f32_16x16x32_bf16(a0, bb.v, acc[0][nf], 0, 0, 0);
      acc[1][nf] = __builtin_amdgcn_mfma_f32_16x16x32_bf16(a1, bb.v, acc[1][nf], 0, 0, 0);
      acc[2][nf] = __builtin_amdgcn_mfma_f32_16x16x32_bf16(a2, bb.v, acc[2][nf], 0, 0, 0);
      acc[3][nf] = __builtin_amdgcn_mfma_f32_16x16x32_bf16(a3, bb.v, acc[3][nf], 0, 0, 0);
    }
  }

  MFMA_EPILOGUE(acc, x1b)
}

// ---------------- conv2: MFMA implicit GEMM (50->50), 512 thr, tile 16x4x8, dbuf ----------------
__global__ __launch_bounds__(512) void conv2_mfma(const unsigned short* __restrict__ x1b,
                                                  const unsigned short* __restrict__ wtm,
                                                  unsigned short* __restrict__ x2b) {
  __shared__ char sh[2][34560];
  const int tid = threadIdx.x;
  const int lane = tid & 63;
  const int wv = tid >> 6;          // wave id = d_local (0..7)
  const int ww = lane & 15;
  const int kb = lane >> 4;
  MFMA_BLOCKIDD

  MFMA_PREPD(x1b)

  f32x4 acc[4][4];
#pragma unroll
  for (int mf = 0; mf < 4; ++mf)
#pragma unroll
    for (int nf = 0; nf < 4; ++nf) acc[mf][nf] = (f32x4)0.f;

  const int nb0 = wv * 3456 + ww * 16;

  MFMA_STAGED_TO(x1b, 0, sh[0])
  __syncthreads();

  for (int g = 0; g < 4; ++g) {
    if (g < 3) { MFMA_STAGED_TO(x1b, g + 1, sh[(g + 1) & 1]) }
    const char* buf = sh[g & 1];
#pragma unroll
    for (int c = 0; c < 14; ++c) {
      bf16x8 a0 = *(const bf16x8*)(wtm + ((((g * 14 + c) * 4 + 0) * 64 + lane) << 3));
      bf16x8 a1 = *(const bf16x8*)(wtm + ((((g * 14 + c) * 4 + 1) * 64 + lane) << 3));
      bf16x8 a2 = *(const bf16x8*)(wtm + ((((g * 14 + c) * 4 + 2) * 64 + lane) << 3));
      bf16x8 a3 = *(const bf16x8*)(wtm + ((((g * 14 + c) * 4 + 3) * 64 + lane) << 3));
      TAP_ADDRD
      const char* bp = buf + nb0 + rb;
      bf16x8 b0 = *(const bf16x8*)(bp);
      bf16x8 b1 = *(const bf16x8*)(bp + 576);
      bf16x8 b2 = *(const bf16x8*)(bp + 2 * 576);
      bf16x8 b3 = *(const bf16x8*)(bp + 3 * 576);
#define MFMA_ROW(MF, AF)                                                              \
      acc[MF][0] = __builtin_amdgcn_mfma_f32_16x16x32_bf16(AF, b0, acc[MF][0], 0, 0, 0); \
      acc[MF][1] = __builtin_amdgcn_mfma_f32_16x16x32_bf16(AF, b1, acc[MF][1], 0, 0, 0); \
      acc[MF][2] = __builtin_amdgcn_mfma_f32_16x16x32_bf16(AF, b2, acc[MF][2], 0, 0, 0); \
      acc[MF][3] = __builtin_amdgcn_mfma_f32_16x16x32_bf16(AF, b3, acc[MF][3], 0, 0, 0);
      MFMA_ROW(0, a0)
      MFMA_ROW(1, a1)
      MFMA_ROW(2, a2)
      MFMA_ROW(3, a3)
#undef MFMA_ROW
    }
    if (g < 3) __syncthreads();
  }

  MFMA_EPILOGUE(acc, x2b)
}

// ---------------- conv3: MFMA (50->1, m=0 live), 512 thr, tile 16x4x8, dbuf ----------------
__global__ __launch_bounds__(512) void conv3_mfma(const unsigned short* __restrict__ x2b,
                                                  const unsigned short* __restrict__ w3m,
                                                  float* __restrict__ residual,
                                                  float* __restrict__ resOut) {
  __shared__ char sh[2][34560];
  const int tid = threadIdx.x;
  const int lane = tid & 63;
  const int wv = tid >> 6;
  const int ww = lane & 15;
  const int kb = lane >> 4;
  MFMA_BLOCKIDD

  MFMA_PREPD(x2b)

  f32x4 acc[4];
#pragma unroll
  for (int nf = 0; nf < 4; ++nf) acc[nf] = (f32x4)0.f;

  const int nb0 = wv * 3456 + ww * 16;

  MFMA_STAGED_TO(x2b, 0, sh[0])
  __syncthreads();

  for (int g = 0; g < 4; ++g) {
    if (g < 3) { MFMA_STAGED_TO(x2b, g + 1, sh[(g + 1) & 1]) }
    const char* buf = sh[g & 1];
#pragma unroll
    for (int c = 0; c < 14; ++c) {
      bf16x8 a0 = *(const bf16x8*)(w3m + (((g * 14 + c) * 64 + lane) << 3));
      TAP_ADDRD
      const char* bp = buf + nb0 + rb;
      bf16x8 b0 = *(const bf16x8*)(bp);
      bf16x8 b1 = *(const bf16x8*)(bp + 576);
      bf16x8 b2 = *(const bf16x8*)(bp + 2 * 576);
      bf16x8 b3 = *(const bf16x8*)(bp + 3 * 576);
      acc[0] = __builtin_amdgcn_mfma_f32_16x16x32_bf16(a0, b0, acc[0], 0, 0, 0);
      acc[1] = __builtin_amdgcn_mfma_f32_16x16x32_bf16(a0, b1, acc[1], 0, 0, 0);
      acc[2] = __builtin_amdgcn_mfma_f32_16x16x32_bf16(a0, b2, acc[2], 0, 0, 0);
      acc[3] = __builtin_amdgcn_mfma_f32_16x16x32_bf16(a0, b3, acc[3], 0, 0, 0);
    }
    if (g < 3) __syncthreads();
  }

  if (lane < 16) {
#pragma unroll
    for (int nf = 0; nf < 4; ++nf) {
      int idx = ((d0 + wv) << 12) + ((h0 + nf) << 6) + (w0 + ww);
      float nr = residual[idx] + acc[nf][0] * 0.1f;
      residual[idx] = nr;
      resOut[idx] = nr;
    }
  }
}

// ---------------- fused res_def warp + phi warp + image update (+ cin_b pack) ----------------
__global__ void rp_fused_kernel(const float* __restrict__ rdOld, const float* __restrict__ v,
                                const float* __restrict__ residual,
                                const float* __restrict__ phiOld, float* __restrict__ phiNew,
                                const float* __restrict__ src, const float* __restrict__ seg,
                                const float* __restrict__ tgt,
                                float* __restrict__ rdNew, float* __restrict__ image,
                                unsigned short* __restrict__ cinb, int doSample) {
  int idx = blockIdx.x * 256 + threadIdx.x;
  int d = idx >> 12, h = (idx >> 6) & 63, w = idx & 63;
  const float step = 2.0f / 63.0f;
  float rres = residual[idx];

  float val = 0.f;
  if (doSample) {
    int tidx = (w << 12) + (h << 6) + d;
    float gx = (-1.f + w * step) - v[tidx] / 10.0f;
    float gy = (-1.f + h * step) - v[NV + tidx] / 10.0f;
    float gz = (-1.f + d * step) - v[2 * NV + tidx] / 10.0f;
    int id[8]; float wt[8];
    tl_make(gx, gy, gz, 1, 64, 4096, id, wt);
    val = tl_apply(rdOld, id, wt);
  }
  float nr = val + rres;
  rdNew[idx] = nr;

  float gx = (-1.f + d * step) - v[idx] / 10.0f;
  float gy = (-1.f + h * step) - v[NV + idx] / 10.0f;
  float gz = (-1.f + w * step) - v[2 * NV + idx] / 10.0f;
  int id[8]; float wt[8];
  tl_make(gx, gy, gz, 4096, 64, 1, id, wt);
  float px = tl_apply(phiOld, id, wt);
  float py = tl_apply(phiOld + NV, id, wt);
  float pz = tl_apply(phiOld + 2 * NV, id, wt);
  phiNew[idx] = px;
  phiNew[NV + idx] = py;
  phiNew[2 * NV + idx] = pz;

  int id2[8]; float wt2[8];
  tl_make(px, py, pz, 1, 64, 4096, id2, wt2);
  float sval = tl_apply(src, id2, wt2);
  float mval = tl_apply(seg, id2, wt2);
  float img = sval + nr * 4.0e-05f * mval;   // MU^2/L
  image[idx] = img;

  unsigned int u0 = (unsigned int)f2bf(rres) | ((unsigned int)f2bf(img) << 16);
  unsigned int u1 = (unsigned int)f2bf(tgt[idx]);
  *(uint2*)(cinb + (size_t)idx * 4) = make_uint2(u0, u1);
}

// ---------------- weight prep ----------------
__global__ void w1m_kernel(const float* __restrict__ W1, unsigned short* __restrict__ w1m) {
  int gid = blockIdx.x * 256 + threadIdx.x;
  if (gid >= 10 * 4 * 4 * 64 * 8) return;
  int j = gid & 7;
  int l = (gid >> 3) & 63;
  int mf = (gid >> 9) & 3;
  int g = (gid >> 11) & 3;
  int i = gid >> 13;
  int m = mf * 16 + (l & 15);
  int kb = l >> 4;
  int k = 32 * g + 8 * kb + j;
  int tap = k >> 2;
  int ci = k & 3;
  float v = 0.f;
  if (m < 50 && tap < 27 && ci < 3)
    v = W1[(((size_t)i * 50 + m) * 3 + ci) * 27 + tap];
  w1m[gid] = f2bf(v);
}

__global__ void wt2m_kernel(const float* __restrict__ W2, unsigned short* __restrict__ wtm) {
  int gid = blockIdx.x * 256 + threadIdx.x;
  if (gid >= 10 * 4 * 14 * 4 * 64 * 8) return;
  int j = gid & 7;
  int l = (gid >> 3) & 63;
  int mf = (gid >> 9) & 3;
  int rest = gid >> 11;
  int c = rest % 14; rest /= 14;
  int g = rest & 3;  int i = rest >> 2;
  int m = mf * 16 + (l & 15);
  int kb = l >> 4;
  int klocal = c * 32 + kb * 8 + j;
  int tap = klocal >> 4;
  int cil = klocal & 15;
  int ci = g * 16 + cil;
  float v = 0.f;
  if (tap < 27 && ci < 50 && m < 50)
    v = W2[(((size_t)i * 50 + m) * 50 + ci) * 27 + tap];
  wtm[gid] = f2bf(v);
}

__global__ void w3m_kernel(const float* __restrict__ W3, unsigned short* __restrict__ w3m) {
  int gid = blockIdx.x * 256 + threadIdx.x;
  if (gid >= 10 * 4 * 14 * 64 * 8) return;
  int j = gid & 7;
  int l = (gid >> 3) & 63;
  int rest = gid >> 9;
  int c = rest % 14; rest /= 14;
  int g = rest & 3;  int i = rest >> 2;
  int m = l & 15;
  int kb = l >> 4;
  int klocal = c * 32 + kb * 8 + j;
  int tap = klocal >> 4;
  int cil = klocal & 15;
  int ci = g * 16 + cil;
  float v = 0.f;
  if (m == 0 && tap < 27 && ci < 50)
    v = W3[((size_t)i * 50 + ci) * 27 + tap];
  w3m[gid] = f2bf(v);
}

extern "C" void kernel_launch(void* const* d_in, const int* in_sizes, int n_in,
                              void* d_out, int out_size, void* d_ws, size_t ws_size,
                              hipStream_t stream) {
  const float* src = (const float*)d_in[0];
  const float* tgt = (const float*)d_in[1];
  const float* seg = (const float*)d_in[2];
  const float* z0  = (const float*)d_in[3];
  const float* W1  = (const float*)d_in[4];
  const float* W2  = (const float*)d_in[5];
  const float* W3  = (const float*)d_in[6];
  float* out = (float*)d_out;
  float* ws = (float*)d_ws;

  const size_t N = NV;
  float* residual = ws;
  float* image    = ws + N;
  float* rdb[2]   = { ws + 2 * N, ws + 3 * N };
  float* phib[2]  = { ws + 4 * N, ws + 7 * N };
  float* vbuf     = ws + 10 * N;
  float* t1       = ws + 13 * N;
  unsigned short* cinb = (unsigned short*)(ws + 16 * N);
  unsigned short* x1b = (unsigned short*)(ws + 19 * N);
  unsigned short* x2b = (unsigned short*)(ws + 51 * N);
  unsigned short* wt2m = (unsigned short*)(ws + 83 * N);
  unsigned short* w3m  = wt2m + (size_t)10 * 4 * 14 * 4 * 64 * 8;
  unsigned short* w1m  = w3m + (size_t)10 * 4 * 14 * 64 * 8;

  size_t needed = 83 * N * sizeof(float)
                + ((size_t)10 * 4 * 14 * 4 * 64 * 8 + (size_t)10 * 4 * 14 * 64 * 8
                   + (size_t)10 * 4 * 4 * 64 * 8) * 2;
  if (ws_size < needed) return;

  float* out_image  = out;
  float* out_fields = out + N;
  float* out_grads  = out + 31 * N;
  float* out_resid  = out + 61 * N;
  float* out_rd     = out + 72 * N;

  dim3 blk(256);
  dim3 blk2(512);
  dim3 grdN((unsigned)(N / 256));
  dim3 sgrd(16, 64);
  dim3 m1grd(4, 16, 16);
  dim3 m2grd(4, 16, 8);

  init_kernel<<<grdN, blk, 0, stream>>>(src, tgt, z0, residual, image, rdb[0], phib[0],
                                        out_resid, cinb);
  w1m_kernel<<<(10 * 4 * 4 * 64 * 8 + 255) / 256, blk, 0, stream>>>(W1, w1m);
  wt2m_kernel<<<(10 * 4 * 14 * 4 * 64 * 8 + 255) / 256, blk, 0, stream>>>(W2, wt2m);
  w3m_kernel<<<(10 * 4 * 14 * 64 * 8 + 255) / 256, blk, 0, stream>>>(W3, w3m);

  int rc = 0, pc = 0;
  for (int i = 0; i < 10; ++i) {
    gsd_kernel<<<grdN, blk, 0, stream>>>(image, residual, out_grads + (size_t)i * 3 * N, t1);
    smooth_hw<<<sgrd, blk, 0, stream>>>(t1, vbuf, out_fields + (size_t)i * 3 * N);

    conv1_mfma<<<m1grd, blk, 0, stream>>>(cinb, w1m + (size_t)i * 4 * 4 * 64 * 8, x1b);
    conv2_mfma<<<m2grd, blk2, 0, stream>>>(x1b, wt2m + (size_t)i * 4 * 14 * 4 * 64 * 8, x2b);
    conv3_mfma<<<m2grd, blk2, 0, stream>>>(x2b, w3m + (size_t)i * 4 * 14 * 64 * 8, residual,
                                           out_resid + (size_t)(i + 1) * N);

    float* rdNew = (i == 9) ? out_rd : rdb[1 - rc];
    float* imgNew = (i == 9) ? out_image : image;
    rp_fused_kernel<<<grdN, blk, 0, stream>>>(rdb[rc], vbuf, residual, phib[pc],
                                              phib[1 - pc], src, seg, tgt, rdNew, imgNew,
                                              cinb, i > 0 ? 1 : 0);
    rc = 1 - rc;
    pc = 1 - pc;
  }
}

// Round 13
// 1518.415 us; speedup vs baseline: 1.1147x; 1.1147x over previous
//
#include <hip/hip_runtime.h>

#define NV 262144          // 64^3

using bf16x8 = __attribute__((ext_vector_type(8))) short;
using f32x4  = __attribute__((ext_vector_type(4))) float;

typedef const __attribute__((address_space(1))) unsigned int* gua_t;
typedef __attribute__((address_space(3))) unsigned int* lua_t;

static __device__ __forceinline__ void gld16(const void* g, void* l) {
  __builtin_amdgcn_global_load_lds((gua_t)g, (lua_t)l, 16, 0, 0);
}

static __device__ __forceinline__ unsigned short f2bf(float x) {
  unsigned int u = __float_as_uint(x);
  unsigned int r = (u + 0x7FFFu + ((u >> 16) & 1u)) >> 16;
  return (unsigned short)r;
}

// ---------------- Gaussian weights (13-tap, sigma=2) ----------------
static __device__ __forceinline__ void gauss_weights(float K[13]) {
  float s = 0.f;
#pragma unroll
  for (int j = 0; j < 13; ++j) {
    float r = (float)(j - 6);
    K[j] = expf(-0.125f * r * r);
    s += K[j];
  }
#pragma unroll
  for (int j = 0; j < 13; ++j) K[j] = K[j] / s;
}

// ---------------- trilinear helpers ----------------
static __device__ __forceinline__ void tl_make(float gx, float gy, float gz,
                                               int sx, int sy, int sz,
                                               int id[8], float wt[8]) {
  float x = fminf(fmaxf((gx + 1.0f) * 0.5f * 63.0f, 0.0f), 63.0f);
  float y = fminf(fmaxf((gy + 1.0f) * 0.5f * 63.0f, 0.0f), 63.0f);
  float z = fminf(fmaxf((gz + 1.0f) * 0.5f * 63.0f, 0.0f), 63.0f);
  float x0f = floorf(x), y0f = floorf(y), z0f = floorf(z);
  int x0 = (int)x0f, y0 = (int)y0f, z0 = (int)z0f;
  int x1 = min(x0 + 1, 63), y1 = min(y0 + 1, 63), z1 = min(z0 + 1, 63);
  float wx = x - x0f, wy = y - y0f, wz = z - z0f;
  float ux = 1.f - wx, uy = 1.f - wy, uz = 1.f - wz;
  int X0 = x0 * sx, X1 = x1 * sx, Y0 = y0 * sy, Y1 = y1 * sy, Z0 = z0 * sz, Z1 = z1 * sz;
  id[0] = Z0 + Y0 + X0; wt[0] = uz * uy * ux;
  id[1] = Z0 + Y0 + X1; wt[1] = uz * uy * wx;
  id[2] = Z0 + Y1 + X0; wt[2] = uz * wy * ux;
  id[3] = Z0 + Y1 + X1; wt[3] = uz * wy * wx;
  id[4] = Z1 + Y0 + X0; wt[4] = wz * uy * ux;
  id[5] = Z1 + Y0 + X1; wt[5] = wz * uy * wx;
  id[6] = Z1 + Y1 + X0; wt[6] = wz * wy * ux;
  id[7] = Z1 + Y1 + X1; wt[7] = wz * wy * wx;
}

static __device__ __forceinline__ float tl_apply(const float* __restrict__ img,
                                                 const int id[8], const float wt[8]) {
  float s = 0.f;
#pragma unroll
  for (int k = 0; k < 8; ++k) s = fmaf(wt[k], img[id[k]], s);
  return s;
}

// ---------------- init (packs cin_b, zeroes the gload zero-page) ----------------
__global__ void init_kernel(const float* __restrict__ src, const float* __restrict__ tgt,
                            const float* __restrict__ z0,
                            float* __restrict__ residual, float* __restrict__ image,
                            float* __restrict__ rd0, float* __restrict__ phi0,
                            float* __restrict__ outRes0, unsigned short* __restrict__ cinb,
                            float* __restrict__ zpf) {
  int idx = blockIdx.x * 256 + threadIdx.x;
  int d = idx >> 12, h = (idx >> 6) & 63, w = idx & 63;
  float z = z0[idx];
  float sv = src[idx];
  residual[idx] = z;
  outRes0[idx] = z;
  image[idx] = sv;
  rd0[idx] = 0.f;
  const float step = 2.0f / 63.0f;
  phi0[idx] = -1.f + w * step;
  phi0[NV + idx] = -1.f + h * step;
  phi0[2 * NV + idx] = -1.f + d * step;
  unsigned int u0 = (unsigned int)f2bf(z) | ((unsigned int)f2bf(sv) << 16);
  unsigned int u1 = (unsigned int)f2bf(tgt[idx]);
  *(uint2*)(cinb + (size_t)idx * 4) = make_uint2(u0, u1);
  if (idx < 32) zpf[idx] = 0.f;   // 128-B zero page for OOB gload_lds lanes
}

// ---------------- fused gradient + smooth-D pass (+ grads output at j==6) ----------------
__global__ void gsd_kernel(const float* __restrict__ img, const float* __restrict__ residual,
                           float* __restrict__ gout, float* __restrict__ t1) {
  int idx = blockIdx.x * 256 + threadIdx.x;
  int d = idx >> 12, h = (idx >> 6) & 63, w = idx & 63;
  float K[13]; gauss_weights(K);
  int wp = min(w + 1, 63), wm = max(w - 1, 0);
  int hp = min(h + 1, 63), hm = max(h - 1, 0);
  float a0 = 0.f, a1 = 0.f, a2 = 0.f;
#pragma unroll
  for (int j = 0; j < 13; ++j) {
    int dd = d + j - 6;
    if ((unsigned)dd < 64u) {
      int b = (dd << 12) + (h << 6);
      int dp = min(dd + 1, 63), dm = max(dd - 1, 0);
      float gx = 0.5f * (img[b + wp] - img[b + wm]);
      float gy = 0.5f * (img[(dd << 12) + (hp << 6) + w] - img[(dd << 12) + (hm << 6) + w]);
      float gz = 0.5f * (img[(dp << 12) + (h << 6) + w] - img[(dm << 12) + (h << 6) + w]);
      float r = residual[b + w];
      if (j == 6) {
        gout[idx] = gx; gout[NV + idx] = gy; gout[2 * NV + idx] = gz;
      }
      a0 = fmaf(K[j], -r * gx, a0);
      a1 = fmaf(K[j], -r * gy, a1);
      a2 = fmaf(K[j], -r * gz, a2);
    }
  }
  t1[idx] = a0; t1[NV + idx] = a1; t1[2 * NV + idx] = a2;
}

// ---------------- fused smooth-H + smooth-W + fields output ----------------
__global__ __launch_bounds__(256) void smooth_hw(const float* __restrict__ t1,
                                                 float* __restrict__ vbuf,
                                                 float* __restrict__ fout) {
  __shared__ float shin[16][64];
  __shared__ float shh[4][64];
  int w = threadIdx.x & 63;
  int ty = threadIdx.x >> 6;
  int h0 = blockIdx.x * 4;
  int d  = blockIdx.y;
  float K[13]; gauss_weights(K);
  for (int c = 0; c < 3; ++c) {
    __syncthreads();
    const float* tc = t1 + (size_t)c * NV + (d << 12);
    for (int r = ty; r < 16; r += 4) {
      int hh = h0 - 6 + r;
      shin[r][w] = ((unsigned)hh < 64u) ? tc[(hh << 6) + w] : 0.f;
    }
    __syncthreads();
    float acc = 0.f;
#pragma unroll
    for (int j = 0; j < 13; ++j) {
      int hh = h0 + ty + j - 6;
      if ((unsigned)hh < 64u) acc = fmaf(K[j], shin[ty + j][w], acc);
    }
    shh[ty][w] = acc;
    __syncthreads();
    float o = 0.f;
#pragma unroll
    for (int j = 0; j < 13; ++j) {
      int wj = w + j - 6;
      if ((unsigned)wj < 64u) o = fmaf(K[j], shh[ty][wj], o);
    }
    int h = h0 + ty;
    vbuf[(size_t)c * NV + (d << 12) + (h << 6) + w] = o;
    fout[((size_t)(w << 12) + (h << 6) + d) * 3 + c] = o;
  }
}

// ============ MFMA helpers (R10 geometry: tile 16x4x4, halo 18x6x6, channel-last bf16) ============
// LDS layout byte-identical to R10: lds[S*16], S = ((dd*6+hh)*2+q)*18 + wws, S < 1296.
// Buffer padded to 1536 slots (24576 B) so each wave owns 6 x 64-slot gload_lds chunks.
// gp[k] = per-lane GLOBAL src for slot S = wv*384 + k*64 + lane (zero-page if OOB/pad).
#define MFMA_PREP_G(XB, ZP)                                                        \
  const unsigned short* gp[6];                                                     \
  _Pragma("unroll")                                                                \
  for (int k = 0; k < 6; ++k) {                                                    \
    int S = wv * 384 + k * 64 + lane;                                              \
    int wws = S % 18; int t = S / 18; int q = t & 1; int dhh = t >> 1;             \
    int hh = dhh % 6; int dd = dhh / 6;                                            \
    int gz = d0 + dd - 1, gy = h0 + hh - 1, gx = w0 + wws - 1;                     \
    bool ok = (S < 1296) && ((unsigned)gz < 64u) && ((unsigned)gy < 64u) && ((unsigned)gx < 64u); \
    gp[k] = ok ? ((XB) + ((((gz << 12) + (gy << 6) + gx) << 6) + q * 8)) : (ZP);   \
  }

// async stage of group G into DSTBUF (no registers held; lands by next barrier)
#define MFMA_ISSUE(G, DSTBUF)                                                      \
  _Pragma("unroll")                                                                \
  for (int k = 0; k < 6; ++k)                                                      \
    gld16(gp[k] + (G) * 16, (DSTBUF) + wv * 6144 + k * 1024);

#define TAP_ADDR                                                                   \
  int tap = 2 * c + (kb >> 1);                                                     \
  int tapc = min(tap, 26);                                                         \
  int kd = (tapc * 57) >> 9;                                                       \
  int rem = tapc - kd * 9;                                                         \
  int kh = (rem * 43) >> 7;                                                        \
  int kw = rem - kh * 3;                                                           \
  int rb = ((kd * 6 + kh) * 2 + (kb & 1)) * 288 + kw * 16;

// XCD-aware bijective swizzle (nwg=1024, 128-chunk per XCD -> d-slab L2 locality)
#define MFMA_BLOCKID                                                               \
  int f = blockIdx.x + 4 * (blockIdx.y + 16 * blockIdx.z);                         \
  int nid = (f & 7) * 128 + (f >> 3);                                              \
  const int w0 = (nid & 3) * 16, h0 = ((nid >> 2) & 15) * 4, d0 = (nid >> 6) * 4;

// channel-last bf16 epilogue (m = mf*16 + kb*4 + r, n = ww)
#define MFMA_EPILOGUE(ACC, XOUT)                                                   \
  _Pragma("unroll")                                                                \
  for (int nf = 0; nf < 4; ++nf) {                                                 \
    int idx = ((d0 + wv) << 12) + ((h0 + nf) << 6) + (w0 + ww);                    \
    unsigned int base = (unsigned int)idx * 64u + kb * 4u;                         \
    _Pragma("unroll")                                                              \
    for (int mf = 0; mf < 4; ++mf) {                                               \
      float v0 = ACC[mf][nf][0], v1 = ACC[mf][nf][1];                              \
      float v2 = ACC[mf][nf][2], v3 = ACC[mf][nf][3];                              \
      v0 = (v0 >= 0.f) ? v0 : 0.01f * v0;                                          \
      v1 = (v1 >= 0.f) ? v1 : 0.01f * v1;                                          \
      v2 = (v2 >= 0.f) ? v2 : 0.01f * v2;                                          \
      v3 = (v3 >= 0.f) ? v3 : 0.01f * v3;                                          \
      unsigned int u0 = (unsigned int)f2bf(v0) | ((unsigned int)f2bf(v1) << 16);   \
      unsigned int u1 = (unsigned int)f2bf(v2) | ((unsigned int)f2bf(v3) << 16);   \
      *(uint2*)((XOUT) + base + mf * 16u) = make_uint2(u0, u1);                    \
    }                                                                              \
  }

// ---------------- conv1: MFMA implicit GEMM (3ch -> 50), K=128, tile 16x4x4 ----------------
__global__ __launch_bounds__(256) void conv1_mfma(const unsigned short* __restrict__ cinb,
                                                  const unsigned short* __restrict__ w1m,
                                                  unsigned short* __restrict__ x1b) {
  __shared__ char sh[1296 * 8];
  const int tid = threadIdx.x;
  const int lane = tid & 63;
  const int wv = tid >> 6;
  const int ww = lane & 15;
  const int kb = lane >> 4;
  MFMA_BLOCKID

  int gofs[6]; int lofs[6]; bool gok[6]; bool sval[6];
#pragma unroll
  for (int k = 0; k < 6; ++k) {
    int s = tid + k * 256;
    sval[k] = (s < 1296);
    int wws = s % 18; int rest = s / 18;
    int hh = rest % 6; int dd = rest / 6;
    int gz = d0 + dd - 1, gy = h0 + hh - 1, gx = w0 + wws - 1;
    bool ok = sval[k] && ((unsigned)gz < 64u) && ((unsigned)gy < 64u) && ((unsigned)gx < 64u);
    gok[k] = ok;
    gofs[k] = ok ? (((gz << 12) + (gy << 6) + gx) * 4) : 0;
    lofs[k] = s * 8;
  }
  {
    uint2 stg[6];
#pragma unroll
    for (int k = 0; k < 6; ++k)
      stg[k] = gok[k] ? *(const uint2*)(cinb + gofs[k]) : make_uint2(0u, 0u);
#pragma unroll
    for (int k = 0; k < 6; ++k)
      if (sval[k]) *(uint2*)(sh + lofs[k]) = stg[k];
  }
  __syncthreads();

  f32x4 acc[4][4];
#pragma unroll
  for (int mf = 0; mf < 4; ++mf)
#pragma unroll
    for (int nf = 0; nf < 4; ++nf) acc[mf][nf] = (f32x4)0.f;

#pragma unroll
  for (int g = 0; g < 4; ++g) {
    bf16x8 a0 = *(const bf16x8*)(w1m + (((g * 4 + 0) * 64 + lane) << 3));
    bf16x8 a1 = *(const bf16x8*)(w1m + (((g * 4 + 1) * 64 + lane) << 3));
    bf16x8 a2 = *(const bf16x8*)(w1m + (((g * 4 + 2) * 64 + lane) << 3));
    bf16x8 a3 = *(const bf16x8*)(w1m + (((g * 4 + 3) * 64 + lane) << 3));
    int tap0 = 8 * g + 2 * kb;
    int t0 = min(tap0, 26), t1 = min(tap0 + 1, 26);
    int kd0 = (t0 * 57) >> 9; int r0 = t0 - kd0 * 9; int kh0 = (r0 * 43) >> 7; int kw0 = r0 - kh0 * 3;
    int kd1 = (t1 * 57) >> 9; int r1 = t1 - kd1 * 9; int kh1 = (r1 * 43) >> 7; int kw1 = r1 - kh1 * 3;
#pragma unroll
    for (int nf = 0; nf < 4; ++nf) {
      union { uint2 u[2]; bf16x8 v; } bb;
      bb.u[0] = *(const uint2*)(sh + (((wv + kd0) * 6 + (nf + kh0)) * 18 + (ww + kw0)) * 8);
      bb.u[1] = *(const uint2*)(sh + (((wv + kd1) * 6 + (nf + kh1)) * 18 + (ww + kw1)) * 8);
      acc[0][nf] = __builtin_amdgcn_mfma_f32_16x16x32_bf16(a0, bb.v, acc[0][nf], 0, 0, 0);
      acc[1][nf] = __builtin_amdgcn_mfma_f32_16x16x32_bf16(a1, bb.v, acc[1][nf], 0, 0, 0);
      acc[2][nf] = __builtin_amdgcn_mfma_f32_16x16x32_bf16(a2, bb.v, acc[2][nf], 0, 0, 0);
      acc[3][nf] = __builtin_amdgcn_mfma_f32_16x16x32_bf16(a3, bb.v, acc[3][nf], 0, 0, 0);
    }
  }

  MFMA_EPILOGUE(acc, x1b)
}

// ---------------- conv2: MFMA implicit GEMM (50->50), dbuf + async gload_lds staging ----------------
__global__ __launch_bounds__(256) void conv2_mfma(const unsigned short* __restrict__ x1b,
                                                  const unsigned short* __restrict__ wtm,
                                                  unsigned short* __restrict__ x2b,
                                                  const unsigned short* __restrict__ zp) {
  __shared__ char sh[2][24576];
  const int tid = threadIdx.x;
  const int lane = tid & 63;
  const int wv = tid >> 6;
  const int ww = lane & 15;
  const int kb = lane >> 4;
  MFMA_BLOCKID

  MFMA_PREP_G(x1b, zp)

  f32x4 acc[4][4];
#pragma unroll
  for (int mf = 0; mf < 4; ++mf)
#pragma unroll
    for (int nf = 0; nf < 4; ++nf) acc[mf][nf] = (f32x4)0.f;

  const int nb0 = wv * 3456 + ww * 16;

  MFMA_ISSUE(0, sh[0])
  __syncthreads();

  for (int g = 0; g < 4; ++g) {
    if (g < 3) { MFMA_ISSUE(g + 1, sh[(g + 1) & 1]) }
    const char* buf = sh[g & 1];
#pragma unroll
    for (int c = 0; c < 14; ++c) {
      bf16x8 a0 = *(const bf16x8*)(wtm + ((((g * 14 + c) * 4 + 0) * 64 + lane) << 3));
      bf16x8 a1 = *(const bf16x8*)(wtm + ((((g * 14 + c) * 4 + 1) * 64 + lane) << 3));
      bf16x8 a2 = *(const bf16x8*)(wtm + ((((g * 14 + c) * 4 + 2) * 64 + lane) << 3));
      bf16x8 a3 = *(const bf16x8*)(wtm + ((((g * 14 + c) * 4 + 3) * 64 + lane) << 3));
      TAP_ADDR
      const char* bp = buf + nb0 + rb;
      bf16x8 b0 = *(const bf16x8*)(bp);
      bf16x8 b1 = *(const bf16x8*)(bp + 576);
      bf16x8 b2 = *(const bf16x8*)(bp + 2 * 576);
      bf16x8 b3 = *(const bf16x8*)(bp + 3 * 576);
#define MFMA_ROW(MF, AF)                                                              \
      acc[MF][0] = __builtin_amdgcn_mfma_f32_16x16x32_bf16(AF, b0, acc[MF][0], 0, 0, 0); \
      acc[MF][1] = __builtin_amdgcn_mfma_f32_16x16x32_bf16(AF, b1, acc[MF][1], 0, 0, 0); \
      acc[MF][2] = __builtin_amdgcn_mfma_f32_16x16x32_bf16(AF, b2, acc[MF][2], 0, 0, 0); \
      acc[MF][3] = __builtin_amdgcn_mfma_f32_16x16x32_bf16(AF, b3, acc[MF][3], 0, 0, 0);
      MFMA_ROW(0, a0)
      MFMA_ROW(1, a1)
      MFMA_ROW(2, a2)
      MFMA_ROW(3, a3)
#undef MFMA_ROW
    }
    __syncthreads();
  }

  MFMA_EPILOGUE(acc, x2b)
}

// ---------------- conv3: MFMA (50->1, m=0 live), dbuf + async gload_lds staging ----------------
__global__ __launch_bounds__(256) void conv3_mfma(const unsigned short* __restrict__ x2b,
                                                  const unsigned short* __restrict__ w3m,
                                                  float* __restrict__ residual,
                                                  float* __restrict__ resOut,
                                                  const unsigned short* __restrict__ zp) {
  __shared__ char sh[2][24576];
  const int tid = threadIdx.x;
  const int lane = tid & 63;
  const int wv = tid >> 6;
  const int ww = lane & 15;
  const int kb = lane >> 4;
  MFMA_BLOCKID

  MFMA_PREP_G(x2b, zp)

  f32x4 acc[4];
#pragma unroll
  for (int nf = 0; nf < 4; ++nf) acc[nf] = (f32x4)0.f;

  const int nb0 = wv * 3456 + ww * 16;

  MFMA_ISSUE(0, sh[0])
  __syncthreads();

  for (int g = 0; g < 4; ++g) {
    if (g < 3) { MFMA_ISSUE(g + 1, sh[(g + 1) & 1]) }
    const char* buf = sh[g & 1];
#pragma unroll
    for (int c = 0; c < 14; ++c) {
      bf16x8 a0 = *(const bf16x8*)(w3m + (((g * 14 + c) * 64 + lane) << 3));
      TAP_ADDR
      const char* bp = buf + nb0 + rb;
      bf16x8 b0 = *(const bf16x8*)(bp);
      bf16x8 b1 = *(const bf16x8*)(bp + 576);
      bf16x8 b2 = *(const bf16x8*)(bp + 2 * 576);
      bf16x8 b3 = *(const bf16x8*)(bp + 3 * 576);
      acc[0] = __builtin_amdgcn_mfma_f32_16x16x32_bf16(a0, b0, acc[0], 0, 0, 0);
      acc[1] = __builtin_amdgcn_mfma_f32_16x16x32_bf16(a0, b1, acc[1], 0, 0, 0);
      acc[2] = __builtin_amdgcn_mfma_f32_16x16x32_bf16(a0, b2, acc[2], 0, 0, 0);
      acc[3] = __builtin_amdgcn_mfma_f32_16x16x32_bf16(a0, b3, acc[3], 0, 0, 0);
    }
    __syncthreads();
  }

  if (lane < 16) {
#pragma unroll
    for (int nf = 0; nf < 4; ++nf) {
      int idx = ((d0 + wv) << 12) + ((h0 + nf) << 6) + (w0 + ww);
      float nr = residual[idx] + acc[nf][0] * 0.1f;
      residual[idx] = nr;
      resOut[idx] = nr;
    }
  }
}

// ---------------- fused res_def warp + phi warp + image update (+ cin_b pack) ----------------
__global__ void rp_fused_kernel(const float* __restrict__ rdOld, const float* __restrict__ v,
                                const float* __restrict__ residual,
                                const float* __restrict__ phiOld, float* __restrict__ phiNew,
                                const float* __restrict__ src, const float* __restrict__ seg,
                                const float* __restrict__ tgt,
                                float* __restrict__ rdNew, float* __restrict__ image,
                                unsigned short* __restrict__ cinb, int doSample) {
  int idx = blockIdx.x * 256 + threadIdx.x;
  int d = idx >> 12, h = (idx >> 6) & 63, w = idx & 63;
  const float step = 2.0f / 63.0f;
  float rres = residual[idx];

  float val = 0.f;
  if (doSample) {
    int tidx = (w << 12) + (h << 6) + d;
    float gx = (-1.f + w * step) - v[tidx] / 10.0f;
    float gy = (-1.f + h * step) - v[NV + tidx] / 10.0f;
    float gz = (-1.f + d * step) - v[2 * NV + tidx] / 10.0f;
    int id[8]; float wt[8];
    tl_make(gx, gy, gz, 1, 64, 4096, id, wt);
    val = tl_apply(rdOld, id, wt);
  }
  float nr = val + rres;
  rdNew[idx] = nr;

  float gx = (-1.f + d * step) - v[idx] / 10.0f;
  float gy = (-1.f + h * step) - v[NV + idx] / 10.0f;
  float gz = (-1.f + w * step) - v[2 * NV + idx] / 10.0f;
  int id[8]; float wt[8];
  tl_make(gx, gy, gz, 4096, 64, 1, id, wt);
  float px = tl_apply(phiOld, id, wt);
  float py = tl_apply(phiOld + NV, id, wt);
  float pz = tl_apply(phiOld + 2 * NV, id, wt);
  phiNew[idx] = px;
  phiNew[NV + idx] = py;
  phiNew[2 * NV + idx] = pz;

  int id2[8]; float wt2[8];
  tl_make(px, py, pz, 1, 64, 4096, id2, wt2);
  float sval = tl_apply(src, id2, wt2);
  float mval = tl_apply(seg, id2, wt2);
  float img = sval + nr * 4.0e-05f * mval;   // MU^2/L
  image[idx] = img;

  unsigned int u0 = (unsigned int)f2bf(rres) | ((unsigned int)f2bf(img) << 16);
  unsigned int u1 = (unsigned int)f2bf(tgt[idx]);
  *(uint2*)(cinb + (size_t)idx * 4) = make_uint2(u0, u1);
}

// ---------------- weight prep ----------------
__global__ void w1m_kernel(const float* __restrict__ W1, unsigned short* __restrict__ w1m) {
  int gid = blockIdx.x * 256 + threadIdx.x;
  if (gid >= 10 * 4 * 4 * 64 * 8) return;
  int j = gid & 7;
  int l = (gid >> 3) & 63;
  int mf = (gid >> 9) & 3;
  int g = (gid >> 11) & 3;
  int i = gid >> 13;
  int m = mf * 16 + (l & 15);
  int kb = l >> 4;
  int k = 32 * g + 8 * kb + j;
  int tap = k >> 2;
  int ci = k & 3;
  float v = 0.f;
  if (m < 50 && tap < 27 && ci < 3)
    v = W1[(((size_t)i * 50 + m) * 3 + ci) * 27 + tap];
  w1m[gid] = f2bf(v);
}

__global__ void wt2m_kernel(const float* __restrict__ W2, unsigned short* __restrict__ wtm) {
  int gid = blockIdx.x * 256 + threadIdx.x;
  if (gid >= 10 * 4 * 14 * 4 * 64 * 8) return;
  int j = gid & 7;
  int l = (gid >> 3) & 63;
  int mf = (gid >> 9) & 3;
  int rest = gid >> 11;
  int c = rest % 14; rest /= 14;
  int g = rest & 3;  int i = rest >> 2;
  int m = mf * 16 + (l & 15);
  int kb = l >> 4;
  int klocal = c * 32 + kb * 8 + j;
  int tap = klocal >> 4;
  int cil = klocal & 15;
  int ci = g * 16 + cil;
  float v = 0.f;
  if (tap < 27 && ci < 50 && m < 50)
    v = W2[(((size_t)i * 50 + m) * 50 + ci) * 27 + tap];
  wtm[gid] = f2bf(v);
}

__global__ void w3m_kernel(const float* __restrict__ W3, unsigned short* __restrict__ w3m) {
  int gid = blockIdx.x * 256 + threadIdx.x;
  if (gid >= 10 * 4 * 14 * 64 * 8) return;
  int j = gid & 7;
  int l = (gid >> 3) & 63;
  int rest = gid >> 9;
  int c = rest % 14; rest /= 14;
  int g = rest & 3;  int i = rest >> 2;
  int m = l & 15;
  int kb = l >> 4;
  int klocal = c * 32 + kb * 8 + j;
  int tap = klocal >> 4;
  int cil = klocal & 15;
  int ci = g * 16 + cil;
  float v = 0.f;
  if (m == 0 && tap < 27 && ci < 50)
    v = W3[((size_t)i * 50 + ci) * 27 + tap];
  w3m[gid] = f2bf(v);
}

extern "C" void kernel_launch(void* const* d_in, const int* in_sizes, int n_in,
                              void* d_out, int out_size, void* d_ws, size_t ws_size,
                              hipStream_t stream) {
  const float* src = (const float*)d_in[0];
  const float* tgt = (const float*)d_in[1];
  const float* seg = (const float*)d_in[2];
  const float* z0  = (const float*)d_in[3];
  const float* W1  = (const float*)d_in[4];
  const float* W2  = (const float*)d_in[5];
  const float* W3  = (const float*)d_in[6];
  float* out = (float*)d_out;
  float* ws = (float*)d_ws;

  const size_t N = NV;
  float* residual = ws;
  float* image    = ws + N;
  float* rdb[2]   = { ws + 2 * N, ws + 3 * N };
  float* phib[2]  = { ws + 4 * N, ws + 7 * N };
  float* vbuf     = ws + 10 * N;
  float* t1       = ws + 13 * N;
  unsigned short* cinb = (unsigned short*)(ws + 16 * N);
  unsigned short* x1b = (unsigned short*)(ws + 19 * N);
  unsigned short* x2b = (unsigned short*)(ws + 51 * N);
  unsigned short* wt2m = (unsigned short*)(ws + 83 * N);
  unsigned short* w3m  = wt2m + (size_t)10 * 4 * 14 * 4 * 64 * 8;
  unsigned short* w1m  = w3m + (size_t)10 * 4 * 14 * 64 * 8;
  unsigned short* zp   = w1m + (size_t)10 * 4 * 4 * 64 * 8;   // 128-B zero page

  size_t needed = 83 * N * sizeof(float)
                + ((size_t)10 * 4 * 14 * 4 * 64 * 8 + (size_t)10 * 4 * 14 * 64 * 8
                   + (size_t)10 * 4 * 4 * 64 * 8) * 2 + 128;
  if (ws_size < needed) return;

  float* out_image  = out;
  float* out_fields = out + N;
  float* out_grads  = out + 31 * N;
  float* out_resid  = out + 61 * N;
  float* out_rd     = out + 72 * N;

  dim3 blk(256);
  dim3 grdN((unsigned)(N / 256));
  dim3 sgrd(16, 64);
  dim3 m1grd(4, 16, 16);

  init_kernel<<<grdN, blk, 0, stream>>>(src, tgt, z0, residual, image, rdb[0], phib[0],
                                        out_resid, cinb, (float*)zp);
  w1m_kernel<<<(10 * 4 * 4 * 64 * 8 + 255) / 256, blk, 0, stream>>>(W1, w1m);
  wt2m_kernel<<<(10 * 4 * 14 * 4 * 64 * 8 + 255) / 256, blk, 0, stream>>>(W2, wt2m);
  w3m_kernel<<<(10 * 4 * 14 * 64 * 8 + 255) / 256, blk, 0, stream>>>(W3, w3m);

  int rc = 0, pc = 0;
  for (int i = 0; i < 10; ++i) {
    gsd_kernel<<<grdN, blk, 0, stream>>>(image, residual, out_grads + (size_t)i * 3 * N, t1);
    smooth_hw<<<sgrd, blk, 0, stream>>>(t1, vbuf, out_fields + (size_t)i * 3 * N);

    conv1_mfma<<<m1grd, blk, 0, stream>>>(cinb, w1m + (size_t)i * 4 * 4 * 64 * 8, x1b);
    conv2_mfma<<<m1grd, blk, 0, stream>>>(x1b, wt2m + (size_t)i * 4 * 14 * 4 * 64 * 8, x2b, zp);
    conv3_mfma<<<m1grd, blk, 0, stream>>>(x2b, w3m + (size_t)i * 4 * 14 * 64 * 8, residual,
                                          out_resid + (size_t)(i + 1) * N, zp);

    float* rdNew = (i == 9) ? out_rd : rdb[1 - rc];
    float* imgNew = (i == 9) ? out_image : image;
    rp_fused_kernel<<<grdN, blk, 0, stream>>>(rdb[rc], vbuf, residual, phib[pc],
                                              phib[1 - pc], src, seg, tgt, rdNew, imgNew,
                                              cinb, i > 0 ? 1 : 0);
    rc = 1 - rc;
    pc = 1 - pc;
  }
}

// Round 14
// 1402.602 us; speedup vs baseline: 1.2067x; 1.0826x over previous
//
#include <hip/hip_runtime.h>

#define NV 262144          // 64^3

using bf16x8 = __attribute__((ext_vector_type(8))) short;
using f32x4  = __attribute__((ext_vector_type(4))) float;

typedef const __attribute__((address_space(1))) unsigned int* gua_t;
typedef __attribute__((address_space(3))) unsigned int* lua_t;

static __device__ __forceinline__ void gld16(const void* g, void* l) {
  __builtin_amdgcn_global_load_lds((gua_t)g, (lua_t)l, 16, 0, 0);
}

static __device__ __forceinline__ unsigned short f2bf(float x) {
  unsigned int u = __float_as_uint(x);
  unsigned int r = (u + 0x7FFFu + ((u >> 16) & 1u)) >> 16;
  return (unsigned short)r;
}

// ---------------- Gaussian weights (13-tap, sigma=2) ----------------
static __device__ __forceinline__ void gauss_weights(float K[13]) {
  float s = 0.f;
#pragma unroll
  for (int j = 0; j < 13; ++j) {
    float r = (float)(j - 6);
    K[j] = expf(-0.125f * r * r);
    s += K[j];
  }
#pragma unroll
  for (int j = 0; j < 13; ++j) K[j] = K[j] / s;
}

// ---------------- trilinear helpers ----------------
static __device__ __forceinline__ void tl_make(float gx, float gy, float gz,
                                               int sx, int sy, int sz,
                                               int id[8], float wt[8]) {
  float x = fminf(fmaxf((gx + 1.0f) * 0.5f * 63.0f, 0.0f), 63.0f);
  float y = fminf(fmaxf((gy + 1.0f) * 0.5f * 63.0f, 0.0f), 63.0f);
  float z = fminf(fmaxf((gz + 1.0f) * 0.5f * 63.0f, 0.0f), 63.0f);
  float x0f = floorf(x), y0f = floorf(y), z0f = floorf(z);
  int x0 = (int)x0f, y0 = (int)y0f, z0 = (int)z0f;
  int x1 = min(x0 + 1, 63), y1 = min(y0 + 1, 63), z1 = min(z0 + 1, 63);
  float wx = x - x0f, wy = y - y0f, wz = z - z0f;
  float ux = 1.f - wx, uy = 1.f - wy, uz = 1.f - wz;
  int X0 = x0 * sx, X1 = x1 * sx, Y0 = y0 * sy, Y1 = y1 * sy, Z0 = z0 * sz, Z1 = z1 * sz;
  id[0] = Z0 + Y0 + X0; wt[0] = uz * uy * ux;
  id[1] = Z0 + Y0 + X1; wt[1] = uz * uy * wx;
  id[2] = Z0 + Y1 + X0; wt[2] = uz * wy * ux;
  id[3] = Z0 + Y1 + X1; wt[3] = uz * wy * wx;
  id[4] = Z1 + Y0 + X0; wt[4] = wz * uy * ux;
  id[5] = Z1 + Y0 + X1; wt[5] = wz * uy * wx;
  id[6] = Z1 + Y1 + X0; wt[6] = wz * wy * ux;
  id[7] = Z1 + Y1 + X1; wt[7] = wz * wy * wx;
}

static __device__ __forceinline__ float tl_apply(const float* __restrict__ img,
                                                 const int id[8], const float wt[8]) {
  float s = 0.f;
#pragma unroll
  for (int k = 0; k < 8; ++k) s = fmaf(wt[k], img[id[k]], s);
  return s;
}

// ---------------- init (packs cin_b, zeroes the gload zero-page) ----------------
__global__ void init_kernel(const float* __restrict__ src, const float* __restrict__ tgt,
                            const float* __restrict__ z0,
                            float* __restrict__ residual, float* __restrict__ image,
                            float* __restrict__ rd0, float* __restrict__ phi0,
                            float* __restrict__ outRes0, unsigned short* __restrict__ cinb,
                            float* __restrict__ zpf) {
  int idx = blockIdx.x * 256 + threadIdx.x;
  int d = idx >> 12, h = (idx >> 6) & 63, w = idx & 63;
  float z = z0[idx];
  float sv = src[idx];
  residual[idx] = z;
  outRes0[idx] = z;
  image[idx] = sv;
  rd0[idx] = 0.f;
  const float step = 2.0f / 63.0f;
  phi0[idx] = -1.f + w * step;
  phi0[NV + idx] = -1.f + h * step;
  phi0[2 * NV + idx] = -1.f + d * step;
  unsigned int u0 = (unsigned int)f2bf(z) | ((unsigned int)f2bf(sv) << 16);
  unsigned int u1 = (unsigned int)f2bf(tgt[idx]);
  *(uint2*)(cinb + (size_t)idx * 4) = make_uint2(u0, u1);
  if (idx < 32) zpf[idx] = 0.f;   // 128-B zero page for OOB gload_lds lanes
}

// ---------------- fused gradient + smooth-D pass (+ grads output at j==6) ----------------
__global__ void gsd_kernel(const float* __restrict__ img, const float* __restrict__ residual,
                           float* __restrict__ gout, float* __restrict__ t1) {
  int idx = blockIdx.x * 256 + threadIdx.x;
  int d = idx >> 12, h = (idx >> 6) & 63, w = idx & 63;
  float K[13]; gauss_weights(K);
  int wp = min(w + 1, 63), wm = max(w - 1, 0);
  int hp = min(h + 1, 63), hm = max(h - 1, 0);
  float a0 = 0.f, a1 = 0.f, a2 = 0.f;
#pragma unroll
  for (int j = 0; j < 13; ++j) {
    int dd = d + j - 6;
    if ((unsigned)dd < 64u) {
      int b = (dd << 12) + (h << 6);
      int dp = min(dd + 1, 63), dm = max(dd - 1, 0);
      float gx = 0.5f * (img[b + wp] - img[b + wm]);
      float gy = 0.5f * (img[(dd << 12) + (hp << 6) + w] - img[(dd << 12) + (hm << 6) + w]);
      float gz = 0.5f * (img[(dp << 12) + (h << 6) + w] - img[(dm << 12) + (h << 6) + w]);
      float r = residual[b + w];
      if (j == 6) {
        gout[idx] = gx; gout[NV + idx] = gy; gout[2 * NV + idx] = gz;
      }
      a0 = fmaf(K[j], -r * gx, a0);
      a1 = fmaf(K[j], -r * gy, a1);
      a2 = fmaf(K[j], -r * gz, a2);
    }
  }
  t1[idx] = a0; t1[NV + idx] = a1; t1[2 * NV + idx] = a2;
}

// ---------------- fused smooth-H + smooth-W + fields output ----------------
__global__ __launch_bounds__(256) void smooth_hw(const float* __restrict__ t1,
                                                 float* __restrict__ vbuf,
                                                 float* __restrict__ fout) {
  __shared__ float shin[16][64];
  __shared__ float shh[4][64];
  int w = threadIdx.x & 63;
  int ty = threadIdx.x >> 6;
  int h0 = blockIdx.x * 4;
  int d  = blockIdx.y;
  float K[13]; gauss_weights(K);
  for (int c = 0; c < 3; ++c) {
    __syncthreads();
    const float* tc = t1 + (size_t)c * NV + (d << 12);
    for (int r = ty; r < 16; r += 4) {
      int hh = h0 - 6 + r;
      shin[r][w] = ((unsigned)hh < 64u) ? tc[(hh << 6) + w] : 0.f;
    }
    __syncthreads();
    float acc = 0.f;
#pragma unroll
    for (int j = 0; j < 13; ++j) {
      int hh = h0 + ty + j - 6;
      if ((unsigned)hh < 64u) acc = fmaf(K[j], shin[ty + j][w], acc);
    }
    shh[ty][w] = acc;
    __syncthreads();
    float o = 0.f;
#pragma unroll
    for (int j = 0; j < 13; ++j) {
      int wj = w + j - 6;
      if ((unsigned)wj < 64u) o = fmaf(K[j], shh[ty][wj], o);
    }
    int h = h0 + ty;
    vbuf[(size_t)c * NV + (d << 12) + (h << 6) + w] = o;
    fout[((size_t)(w << 12) + (h << 6) + d) * 3 + c] = o;
  }
}

// ============ MFMA helpers (tile 16x4x4, halo 18x6x6, channel-last bf16) ============
// 7-group K repack: group g = ci8 block g (ci = 8g..8g+7; 50 real, pad to 56),
// per group 7 c-iters, tap = 4c + kb (27 real of 28 slots). No ci interleave.
// LDS per buffer: 648 halo voxels x 16 B (one ci8 block) = 10368 B, padded to 12288.
// slot S = (dd*6+hh)*18 + wws; addr = S*16.
#define MFMA_PREP_G7(XB, ZP)                                                       \
  const unsigned short* gp[3];                                                     \
  _Pragma("unroll")                                                                \
  for (int k = 0; k < 3; ++k) {                                                    \
    int S = wv * 192 + k * 64 + lane;                                              \
    int wws = S % 18; int t = S / 18;                                              \
    int hh = t % 6; int dd = t / 6;                                                \
    int gz = d0 + dd - 1, gy = h0 + hh - 1, gx = w0 + wws - 1;                     \
    bool ok = (S < 648) && ((unsigned)gz < 64u) && ((unsigned)gy < 64u) && ((unsigned)gx < 64u); \
    gp[k] = ok ? ((XB) + (((gz << 12) + (gy << 6) + gx) << 6)) : (ZP);             \
  }

// async stage of ci8-group G into DSTBUF (wave wv owns slots [wv*192, wv*192+192))
#define MFMA_ISSUE7(G, DSTBUF)                                                     \
  _Pragma("unroll")                                                                \
  for (int k = 0; k < 3; ++k)                                                      \
    gld16(gp[k] + (G) * 8, (DSTBUF) + wv * 3072 + k * 1024);

// tap = 4c + kb; voxel offset (kd,kh,kw): dd stride 1728, hh stride 288, wws stride 16
#define TAP_ADDR7                                                                  \
  int tap = 4 * c + kb;                                                            \
  int tapc = min(tap, 26);                                                         \
  int kd = (tapc * 57) >> 9;                                                       \
  int rem = tapc - kd * 9;                                                         \
  int kh = (rem * 43) >> 7;                                                        \
  int kw = rem - kh * 3;                                                           \
  int rb = kd * 1728 + kh * 288 + kw * 16;

// XCD-aware bijective swizzle (nwg=1024, 128-chunk per XCD -> d-slab L2 locality)
#define MFMA_BLOCKID                                                               \
  int f = blockIdx.x + 4 * (blockIdx.y + 16 * blockIdx.z);                         \
  int nid = (f & 7) * 128 + (f >> 3);                                              \
  const int w0 = (nid & 3) * 16, h0 = ((nid >> 2) & 15) * 4, d0 = (nid >> 6) * 4;

// channel-last bf16 epilogue (m = mf*16 + kb*4 + r, n = ww)
#define MFMA_EPILOGUE(ACC, XOUT)                                                   \
  _Pragma("unroll")                                                                \
  for (int nf = 0; nf < 4; ++nf) {                                                 \
    int idx = ((d0 + wv) << 12) + ((h0 + nf) << 6) + (w0 + ww);                    \
    unsigned int base = (unsigned int)idx * 64u + kb * 4u;                         \
    _Pragma("unroll")                                                              \
    for (int mf = 0; mf < 4; ++mf) {                                               \
      float v0 = ACC[mf][nf][0], v1 = ACC[mf][nf][1];                              \
      float v2 = ACC[mf][nf][2], v3 = ACC[mf][nf][3];                              \
      v0 = (v0 >= 0.f) ? v0 : 0.01f * v0;                                          \
      v1 = (v1 >= 0.f) ? v1 : 0.01f * v1;                                          \
      v2 = (v2 >= 0.f) ? v2 : 0.01f * v2;                                          \
      v3 = (v3 >= 0.f) ? v3 : 0.01f * v3;                                          \
      unsigned int u0 = (unsigned int)f2bf(v0) | ((unsigned int)f2bf(v1) << 16);   \
      unsigned int u1 = (unsigned int)f2bf(v2) | ((unsigned int)f2bf(v3) << 16);   \
      *(uint2*)((XOUT) + base + mf * 16u) = make_uint2(u0, u1);                    \
    }                                                                              \
  }

// ---------------- conv1: MFMA implicit GEMM (3ch -> 50), K=128, tile 16x4x4 ----------------
__global__ __launch_bounds__(256) void conv1_mfma(const unsigned short* __restrict__ cinb,
                                                  const unsigned short* __restrict__ w1m,
                                                  unsigned short* __restrict__ x1b) {
  __shared__ char sh[1296 * 8];
  const int tid = threadIdx.x;
  const int lane = tid & 63;
  const int wv = tid >> 6;
  const int ww = lane & 15;
  const int kb = lane >> 4;
  MFMA_BLOCKID

  int gofs[6]; int lofs[6]; bool gok[6]; bool sval[6];
#pragma unroll
  for (int k = 0; k < 6; ++k) {
    int s = tid + k * 256;
    sval[k] = (s < 1296);
    int wws = s % 18; int rest = s / 18;
    int hh = rest % 6; int dd = rest / 6;
    int gz = d0 + dd - 1, gy = h0 + hh - 1, gx = w0 + wws - 1;
    bool ok = sval[k] && ((unsigned)gz < 64u) && ((unsigned)gy < 64u) && ((unsigned)gx < 64u);
    gok[k] = ok;
    gofs[k] = ok ? (((gz << 12) + (gy << 6) + gx) * 4) : 0;
    lofs[k] = s * 8;
  }
  {
    uint2 stg[6];
#pragma unroll
    for (int k = 0; k < 6; ++k)
      stg[k] = gok[k] ? *(const uint2*)(cinb + gofs[k]) : make_uint2(0u, 0u);
#pragma unroll
    for (int k = 0; k < 6; ++k)
      if (sval[k]) *(uint2*)(sh + lofs[k]) = stg[k];
  }
  __syncthreads();

  f32x4 acc[4][4];
#pragma unroll
  for (int mf = 0; mf < 4; ++mf)
#pragma unroll
    for (int nf = 0; nf < 4; ++nf) acc[mf][nf] = (f32x4)0.f;

#pragma unroll
  for (int g = 0; g < 4; ++g) {
    bf16x8 a0 = *(const bf16x8*)(w1m + (((g * 4 + 0) * 64 + lane) << 3));
    bf16x8 a1 = *(const bf16x8*)(w1m + (((g * 4 + 1) * 64 + lane) << 3));
    bf16x8 a2 = *(const bf16x8*)(w1m + (((g * 4 + 2) * 64 + lane) << 3));
    bf16x8 a3 = *(const bf16x8*)(w1m + (((g * 4 + 3) * 64 + lane) << 3));
    int tap0 = 8 * g + 2 * kb;
    int t0 = min(tap0, 26), t1 = min(tap0 + 1, 26);
    int kd0 = (t0 * 57) >> 9; int r0 = t0 - kd0 * 9; int kh0 = (r0 * 43) >> 7; int kw0 = r0 - kh0 * 3;
    int kd1 = (t1 * 57) >> 9; int r1 = t1 - kd1 * 9; int kh1 = (r1 * 43) >> 7; int kw1 = r1 - kh1 * 3;
#pragma unroll
    for (int nf = 0; nf < 4; ++nf) {
      union { uint2 u[2]; bf16x8 v; } bb;
      bb.u[0] = *(const uint2*)(sh + (((wv + kd0) * 6 + (nf + kh0)) * 18 + (ww + kw0)) * 8);
      bb.u[1] = *(const uint2*)(sh + (((wv + kd1) * 6 + (nf + kh1)) * 18 + (ww + kw1)) * 8);
      acc[0][nf] = __builtin_amdgcn_mfma_f32_16x16x32_bf16(a0, bb.v, acc[0][nf], 0, 0, 0);
      acc[1][nf] = __builtin_amdgcn_mfma_f32_16x16x32_bf16(a1, bb.v, acc[1][nf], 0, 0, 0);
      acc[2][nf] = __builtin_amdgcn_mfma_f32_16x16x32_bf16(a2, bb.v, acc[2][nf], 0, 0, 0);
      acc[3][nf] = __builtin_amdgcn_mfma_f32_16x16x32_bf16(a3, bb.v, acc[3][nf], 0, 0, 0);
    }
  }

  MFMA_EPILOGUE(acc, x1b)
}

// ---------------- conv2: MFMA implicit GEMM (50->50), 7-group repack, dbuf + gload_lds ----------------
__global__ __launch_bounds__(256) void conv2_mfma(const unsigned short* __restrict__ x1b,
                                                  const unsigned short* __restrict__ wtm,
                                                  unsigned short* __restrict__ x2b,
                                                  const unsigned short* __restrict__ zp) {
  __shared__ char sh[2][12288];
  const int tid = threadIdx.x;
  const int lane = tid & 63;
  const int wv = tid >> 6;
  const int ww = lane & 15;
  const int kb = lane >> 4;
  MFMA_BLOCKID

  MFMA_PREP_G7(x1b, zp)

  f32x4 acc[4][4];
#pragma unroll
  for (int mf = 0; mf < 4; ++mf)
#pragma unroll
    for (int nf = 0; nf < 4; ++nf) acc[mf][nf] = (f32x4)0.f;

  const int nb0 = wv * 1728 + ww * 16;

  MFMA_ISSUE7(0, sh[0])
  __syncthreads();

  for (int g = 0; g < 7; ++g) {
    if (g < 6) { MFMA_ISSUE7(g + 1, sh[(g + 1) & 1]) }
    const char* buf = sh[g & 1];
#pragma unroll
    for (int c = 0; c < 7; ++c) {
      bf16x8 a0 = *(const bf16x8*)(wtm + ((((g * 7 + c) * 4 + 0) * 64 + lane) << 3));
      bf16x8 a1 = *(const bf16x8*)(wtm + ((((g * 7 + c) * 4 + 1) * 64 + lane) << 3));
      bf16x8 a2 = *(const bf16x8*)(wtm + ((((g * 7 + c) * 4 + 2) * 64 + lane) << 3));
      bf16x8 a3 = *(const bf16x8*)(wtm + ((((g * 7 + c) * 4 + 3) * 64 + lane) << 3));
      TAP_ADDR7
      const char* bp = buf + nb0 + rb;
      bf16x8 b0 = *(const bf16x8*)(bp);
      bf16x8 b1 = *(const bf16x8*)(bp + 288);
      bf16x8 b2 = *(const bf16x8*)(bp + 2 * 288);
      bf16x8 b3 = *(const bf16x8*)(bp + 3 * 288);
#define MFMA_ROW(MF, AF)                                                              \
      acc[MF][0] = __builtin_amdgcn_mfma_f32_16x16x32_bf16(AF, b0, acc[MF][0], 0, 0, 0); \
      acc[MF][1] = __builtin_amdgcn_mfma_f32_16x16x32_bf16(AF, b1, acc[MF][1], 0, 0, 0); \
      acc[MF][2] = __builtin_amdgcn_mfma_f32_16x16x32_bf16(AF, b2, acc[MF][2], 0, 0, 0); \
      acc[MF][3] = __builtin_amdgcn_mfma_f32_16x16x32_bf16(AF, b3, acc[MF][3], 0, 0, 0);
      MFMA_ROW(0, a0)
      MFMA_ROW(1, a1)
      MFMA_ROW(2, a2)
      MFMA_ROW(3, a3)
#undef MFMA_ROW
    }
    __syncthreads();
  }

  MFMA_EPILOGUE(acc, x2b)
}

// ---------------- conv3: MFMA (50->1, m=0 live), 7-group repack, dbuf + gload_lds ----------------
__global__ __launch_bounds__(256) void conv3_mfma(const unsigned short* __restrict__ x2b,
                                                  const unsigned short* __restrict__ w3m,
                                                  float* __restrict__ residual,
                                                  float* __restrict__ resOut,
                                                  const unsigned short* __restrict__ zp) {
  __shared__ char sh[2][12288];
  const int tid = threadIdx.x;
  const int lane = tid & 63;
  const int wv = tid >> 6;
  const int ww = lane & 15;
  const int kb = lane >> 4;
  MFMA_BLOCKID

  MFMA_PREP_G7(x2b, zp)

  f32x4 acc[4];
#pragma unroll
  for (int nf = 0; nf < 4; ++nf) acc[nf] = (f32x4)0.f;

  const int nb0 = wv * 1728 + ww * 16;

  MFMA_ISSUE7(0, sh[0])
  __syncthreads();

  for (int g = 0; g < 7; ++g) {
    if (g < 6) { MFMA_ISSUE7(g + 1, sh[(g + 1) & 1]) }
    const char* buf = sh[g & 1];
#pragma unroll
    for (int c = 0; c < 7; ++c) {
      bf16x8 a0 = *(const bf16x8*)(w3m + (((g * 7 + c) * 64 + lane) << 3));
      TAP_ADDR7
      const char* bp = buf + nb0 + rb;
      bf16x8 b0 = *(const bf16x8*)(bp);
      bf16x8 b1 = *(const bf16x8*)(bp + 288);
      bf16x8 b2 = *(const bf16x8*)(bp + 2 * 288);
      bf16x8 b3 = *(const bf16x8*)(bp + 3 * 288);
      acc[0] = __builtin_amdgcn_mfma_f32_16x16x32_bf16(a0, b0, acc[0], 0, 0, 0);
      acc[1] = __builtin_amdgcn_mfma_f32_16x16x32_bf16(a0, b1, acc[1], 0, 0, 0);
      acc[2] = __builtin_amdgcn_mfma_f32_16x16x32_bf16(a0, b2, acc[2], 0, 0, 0);
      acc[3] = __builtin_amdgcn_mfma_f32_16x16x32_bf16(a0, b3, acc[3], 0, 0, 0);
    }
    __syncthreads();
  }

  if (lane < 16) {
#pragma unroll
    for (int nf = 0; nf < 4; ++nf) {
      int idx = ((d0 + wv) << 12) + ((h0 + nf) << 6) + (w0 + ww);
      float nr = residual[idx] + acc[nf][0] * 0.1f;
      residual[idx] = nr;
      resOut[idx] = nr;
    }
  }
}

// ---------------- fused res_def warp + phi warp + image update (+ cin_b pack) ----------------
__global__ void rp_fused_kernel(const float* __restrict__ rdOld, const float* __restrict__ v,
                                const float* __restrict__ residual,
                                const float* __restrict__ phiOld, float* __restrict__ phiNew,
                                const float* __restrict__ src, const float* __restrict__ seg,
                                const float* __restrict__ tgt,
                                float* __restrict__ rdNew, float* __restrict__ image,
                                unsigned short* __restrict__ cinb, int doSample) {
  int idx = blockIdx.x * 256 + threadIdx.x;
  int d = idx >> 12, h = (idx >> 6) & 63, w = idx & 63;
  const float step = 2.0f / 63.0f;
  float rres = residual[idx];

  float val = 0.f;
  if (doSample) {
    int tidx = (w << 12) + (h << 6) + d;
    float gx = (-1.f + w * step) - v[tidx] / 10.0f;
    float gy = (-1.f + h * step) - v[NV + tidx] / 10.0f;
    float gz = (-1.f + d * step) - v[2 * NV + tidx] / 10.0f;
    int id[8]; float wt[8];
    tl_make(gx, gy, gz, 1, 64, 4096, id, wt);
    val = tl_apply(rdOld, id, wt);
  }
  float nr = val + rres;
  rdNew[idx] = nr;

  float gx = (-1.f + d * step) - v[idx] / 10.0f;
  float gy = (-1.f + h * step) - v[NV + idx] / 10.0f;
  float gz = (-1.f + w * step) - v[2 * NV + idx] / 10.0f;
  int id[8]; float wt[8];
  tl_make(gx, gy, gz, 4096, 64, 1, id, wt);
  float px = tl_apply(phiOld, id, wt);
  float py = tl_apply(phiOld + NV, id, wt);
  float pz = tl_apply(phiOld + 2 * NV, id, wt);
  phiNew[idx] = px;
  phiNew[NV + idx] = py;
  phiNew[2 * NV + idx] = pz;

  int id2[8]; float wt2[8];
  tl_make(px, py, pz, 1, 64, 4096, id2, wt2);
  float sval = tl_apply(src, id2, wt2);
  float mval = tl_apply(seg, id2, wt2);
  float img = sval + nr * 4.0e-05f * mval;   // MU^2/L
  image[idx] = img;

  unsigned int u0 = (unsigned int)f2bf(rres) | ((unsigned int)f2bf(img) << 16);
  unsigned int u1 = (unsigned int)f2bf(tgt[idx]);
  *(uint2*)(cinb + (size_t)idx * 4) = make_uint2(u0, u1);
}

// ---------------- weight prep ----------------
__global__ void w1m_kernel(const float* __restrict__ W1, unsigned short* __restrict__ w1m) {
  int gid = blockIdx.x * 256 + threadIdx.x;
  if (gid >= 10 * 4 * 4 * 64 * 8) return;
  int j = gid & 7;
  int l = (gid >> 3) & 63;
  int mf = (gid >> 9) & 3;
  int g = (gid >> 11) & 3;
  int i = gid >> 13;
  int m = mf * 16 + (l & 15);
  int kb = l >> 4;
  int k = 32 * g + 8 * kb + j;
  int tap = k >> 2;
  int ci = k & 3;
  float v = 0.f;
  if (m < 50 && tap < 27 && ci < 3)
    v = W1[(((size_t)i * 50 + m) * 3 + ci) * 27 + tap];
  w1m[gid] = f2bf(v);
}

// wt2m: [i][g7][c7][mf4][lane64][j8]; ci = 8g + j, tap = 4c + kb
__global__ void wt2m_kernel(const float* __restrict__ W2, unsigned short* __restrict__ wtm) {
  int gid = blockIdx.x * 256 + threadIdx.x;
  if (gid >= 10 * 7 * 7 * 4 * 64 * 8) return;
  int j = gid & 7;
  int l = (gid >> 3) & 63;
  int mf = (gid >> 9) & 3;
  int rest = gid >> 11;
  int c = rest % 7; rest /= 7;
  int g = rest % 7; int i = rest / 7;
  int m = mf * 16 + (l & 15);
  int kb = l >> 4;
  int tap = 4 * c + kb;
  int ci = 8 * g + j;
  float v = 0.f;
  if (tap < 27 && ci < 50 && m < 50)
    v = W2[(((size_t)i * 50 + m) * 50 + ci) * 27 + tap];
  wtm[gid] = f2bf(v);
}

// w3m: [i][g7][c7][lane64][j8]; only m==0 rows nonzero
__global__ void w3m_kernel(const float* __restrict__ W3, unsigned short* __restrict__ w3m) {
  int gid = blockIdx.x * 256 + threadIdx.x;
  if (gid >= 10 * 7 * 7 * 64 * 8) return;
  int j = gid & 7;
  int l = (gid >> 3) & 63;
  int rest = gid >> 9;
  int c = rest % 7; rest /= 7;
  int g = rest % 7; int i = rest / 7;
  int m = l & 15;
  int kb = l >> 4;
  int tap = 4 * c + kb;
  int ci = 8 * g + j;
  float v = 0.f;
  if (m == 0 && tap < 27 && ci < 50)
    v = W3[((size_t)i * 50 + ci) * 27 + tap];
  w3m[gid] = f2bf(v);
}

extern "C" void kernel_launch(void* const* d_in, const int* in_sizes, int n_in,
                              void* d_out, int out_size, void* d_ws, size_t ws_size,
                              hipStream_t stream) {
  const float* src = (const float*)d_in[0];
  const float* tgt = (const float*)d_in[1];
  const float* seg = (const float*)d_in[2];
  const float* z0  = (const float*)d_in[3];
  const float* W1  = (const float*)d_in[4];
  const float* W2  = (const float*)d_in[5];
  const float* W3  = (const float*)d_in[6];
  float* out = (float*)d_out;
  float* ws = (float*)d_ws;

  const size_t N = NV;
  const size_t WT2M = (size_t)10 * 7 * 7 * 4 * 64 * 8;   // 1,003,520
  const size_t W3M  = (size_t)10 * 7 * 7 * 64 * 8;       // 250,880
  const size_t W1M  = (size_t)10 * 4 * 4 * 64 * 8;       // 81,920

  float* residual = ws;
  float* image    = ws + N;
  float* rdb[2]   = { ws + 2 * N, ws + 3 * N };
  float* phib[2]  = { ws + 4 * N, ws + 7 * N };
  float* vbuf     = ws + 10 * N;
  float* t1       = ws + 13 * N;
  unsigned short* cinb = (unsigned short*)(ws + 16 * N);
  unsigned short* x1b = (unsigned short*)(ws + 19 * N);
  unsigned short* x2b = (unsigned short*)(ws + 51 * N);
  unsigned short* wt2m = (unsigned short*)(ws + 83 * N);
  unsigned short* w3m  = wt2m + WT2M;
  unsigned short* w1m  = w3m + W3M;
  unsigned short* zp   = w1m + W1M;   // 128-B zero page

  size_t needed = 83 * N * sizeof(float) + (WT2M + W3M + W1M) * 2 + 128;
  if (ws_size < needed) return;

  float* out_image  = out;
  float* out_fields = out + N;
  float* out_grads  = out + 31 * N;
  float* out_resid  = out + 61 * N;
  float* out_rd     = out + 72 * N;

  dim3 blk(256);
  dim3 grdN((unsigned)(N / 256));
  dim3 sgrd(16, 64);
  dim3 m1grd(4, 16, 16);

  init_kernel<<<grdN, blk, 0, stream>>>(src, tgt, z0, residual, image, rdb[0], phib[0],
                                        out_resid, cinb, (float*)zp);
  w1m_kernel<<<(int)((W1M + 255) / 256), blk, 0, stream>>>(W1, w1m);
  wt2m_kernel<<<(int)((WT2M + 255) / 256), blk, 0, stream>>>(W2, wt2m);
  w3m_kernel<<<(int)((W3M + 255) / 256), blk, 0, stream>>>(W3, w3m);

  int rc = 0, pc = 0;
  for (int i = 0; i < 10; ++i) {
    gsd_kernel<<<grdN, blk, 0, stream>>>(image, residual, out_grads + (size_t)i * 3 * N, t1);
    smooth_hw<<<sgrd, blk, 0, stream>>>(t1, vbuf, out_fields + (size_t)i * 3 * N);

    conv1_mfma<<<m1grd, blk, 0, stream>>>(cinb, w1m + (size_t)i * 4 * 4 * 64 * 8, x1b);
    conv2_mfma<<<m1grd, blk, 0, stream>>>(x1b, wt2m + (size_t)i * 7 * 7 * 4 * 64 * 8, x2b, zp);
    conv3_mfma<<<m1grd, blk, 0, stream>>>(x2b, w3m + (size_t)i * 7 * 7 * 64 * 8, residual,
                                          out_resid + (size_t)(i + 1) * N, zp);

    float* rdNew = (i == 9) ? out_rd : rdb[1 - rc];
    float* imgNew = (i == 9) ? out_image : image;
    rp_fused_kernel<<<grdN, blk, 0, stream>>>(rdb[rc], vbuf, residual, phib[pc],
                                              phib[1 - pc], src, seg, tgt, rdNew, imgNew,
                                              cinb, i > 0 ? 1 : 0);
    rc = 1 - rc;
    pc = 1 - pc;
  }
}

// Round 16
// 1398.165 us; speedup vs baseline: 1.2106x; 1.0032x over previous
//
#include <hip/hip_runtime.h>

#define NV 262144          // 64^3

using bf16x8 = __attribute__((ext_vector_type(8))) short;
using f32x4  = __attribute__((ext_vector_type(4))) float;

typedef const __attribute__((address_space(1))) unsigned int* gua_t;
typedef __attribute__((address_space(3))) unsigned int* lua_t;

static __device__ __forceinline__ void gld16(const void* g, void* l) {
  __builtin_amdgcn_global_load_lds((gua_t)g, (lua_t)l, 16, 0, 0);
}

static __device__ __forceinline__ unsigned short f2bf(float x) {
  unsigned int u = __float_as_uint(x);
  unsigned int r = (u + 0x7FFFu + ((u >> 16) & 1u)) >> 16;
  return (unsigned short)r;
}

// ---------------- Gaussian weights (13-tap, sigma=2) ----------------
static __device__ __forceinline__ void gauss_weights(float K[13]) {
  float s = 0.f;
#pragma unroll
  for (int j = 0; j < 13; ++j) {
    float r = (float)(j - 6);
    K[j] = expf(-0.125f * r * r);
    s += K[j];
  }
#pragma unroll
  for (int j = 0; j < 13; ++j) K[j] = K[j] / s;
}

// ---------------- trilinear helpers ----------------
static __device__ __forceinline__ void tl_make(float gx, float gy, float gz,
                                               int sx, int sy, int sz,
                                               int id[8], float wt[8]) {
  float x = fminf(fmaxf((gx + 1.0f) * 0.5f * 63.0f, 0.0f), 63.0f);
  float y = fminf(fmaxf((gy + 1.0f) * 0.5f * 63.0f, 0.0f), 63.0f);
  float z = fminf(fmaxf((gz + 1.0f) * 0.5f * 63.0f, 0.0f), 63.0f);
  float x0f = floorf(x), y0f = floorf(y), z0f = floorf(z);
  int x0 = (int)x0f, y0 = (int)y0f, z0 = (int)z0f;
  int x1 = min(x0 + 1, 63), y1 = min(y0 + 1, 63), z1 = min(z0 + 1, 63);
  float wx = x - x0f, wy = y - y0f, wz = z - z0f;
  float ux = 1.f - wx, uy = 1.f - wy, uz = 1.f - wz;
  int X0 = x0 * sx, X1 = x1 * sx, Y0 = y0 * sy, Y1 = y1 * sy, Z0 = z0 * sz, Z1 = z1 * sz;
  id[0] = Z0 + Y0 + X0; wt[0] = uz * uy * ux;
  id[1] = Z0 + Y0 + X1; wt[1] = uz * uy * wx;
  id[2] = Z0 + Y1 + X0; wt[2] = uz * wy * ux;
  id[3] = Z0 + Y1 + X1; wt[3] = uz * wy * wx;
  id[4] = Z1 + Y0 + X0; wt[4] = wz * uy * ux;
  id[5] = Z1 + Y0 + X1; wt[5] = wz * uy * wx;
  id[6] = Z1 + Y1 + X0; wt[6] = wz * wy * ux;
  id[7] = Z1 + Y1 + X1; wt[7] = wz * wy * wx;
}

static __device__ __forceinline__ float tl_apply(const float* __restrict__ img,
                                                 const int id[8], const float wt[8]) {
  float s = 0.f;
#pragma unroll
  for (int k = 0; k < 8; ++k) s = fmaf(wt[k], img[id[k]], s);
  return s;
}

// ---------------- init (packs cin_b, zeroes the gload zero-page) ----------------
__global__ void init_kernel(const float* __restrict__ src, const float* __restrict__ tgt,
                            const float* __restrict__ z0,
                            float* __restrict__ residual, float* __restrict__ image,
                            float* __restrict__ rd0, float* __restrict__ phi0,
                            float* __restrict__ outRes0, unsigned short* __restrict__ cinb,
                            float* __restrict__ zpf) {
  int idx = blockIdx.x * 256 + threadIdx.x;
  int d = idx >> 12, h = (idx >> 6) & 63, w = idx & 63;
  float z = z0[idx];
  float sv = src[idx];
  residual[idx] = z;
  outRes0[idx] = z;
  image[idx] = sv;
  rd0[idx] = 0.f;
  const float step = 2.0f / 63.0f;
  phi0[idx] = -1.f + w * step;
  phi0[NV + idx] = -1.f + h * step;
  phi0[2 * NV + idx] = -1.f + d * step;
  unsigned int u0 = (unsigned int)f2bf(z) | ((unsigned int)f2bf(sv) << 16);
  unsigned int u1 = (unsigned int)f2bf(tgt[idx]);
  *(uint2*)(cinb + (size_t)idx * 4) = make_uint2(u0, u1);
  if (idx < 32) zpf[idx] = 0.f;   // 128-B zero page for OOB gload_lds lanes
}

// ---------------- fused gradient + smooth-D pass (+ grads output at j==6) ----------------
__global__ void gsd_kernel(const float* __restrict__ img, const float* __restrict__ residual,
                           float* __restrict__ gout, float* __restrict__ t1) {
  int idx = blockIdx.x * 256 + threadIdx.x;
  int d = idx >> 12, h = (idx >> 6) & 63, w = idx & 63;
  float K[13]; gauss_weights(K);
  int wp = min(w + 1, 63), wm = max(w - 1, 0);
  int hp = min(h + 1, 63), hm = max(h - 1, 0);
  float a0 = 0.f, a1 = 0.f, a2 = 0.f;
#pragma unroll
  for (int j = 0; j < 13; ++j) {
    int dd = d + j - 6;
    if ((unsigned)dd < 64u) {
      int b = (dd << 12) + (h << 6);
      int dp = min(dd + 1, 63), dm = max(dd - 1, 0);
      float gx = 0.5f * (img[b + wp] - img[b + wm]);
      float gy = 0.5f * (img[(dd << 12) + (hp << 6) + w] - img[(dd << 12) + (hm << 6) + w]);
      float gz = 0.5f * (img[(dp << 12) + (h << 6) + w] - img[(dm << 12) + (h << 6) + w]);
      float r = residual[b + w];
      if (j == 6) {
        gout[idx] = gx; gout[NV + idx] = gy; gout[2 * NV + idx] = gz;
      }
      a0 = fmaf(K[j], -r * gx, a0);
      a1 = fmaf(K[j], -r * gy, a1);
      a2 = fmaf(K[j], -r * gz, a2);
    }
  }
  t1[idx] = a0; t1[NV + idx] = a1; t1[2 * NV + idx] = a2;
}

// ---------------- fused smooth-H + smooth-W + fields output ----------------
__global__ __launch_bounds__(256) void smooth_hw(const float* __restrict__ t1,
                                                 float* __restrict__ vbuf,
                                                 float* __restrict__ fout) {
  __shared__ float shin[16][64];
  __shared__ float shh[4][64];
  int w = threadIdx.x & 63;
  int ty = threadIdx.x >> 6;
  int h0 = blockIdx.x * 4;
  int d  = blockIdx.y;
  float K[13]; gauss_weights(K);
  for (int c = 0; c < 3; ++c) {
    __syncthreads();
    const float* tc = t1 + (size_t)c * NV + (d << 12);
    for (int r = ty; r < 16; r += 4) {
      int hh = h0 - 6 + r;
      shin[r][w] = ((unsigned)hh < 64u) ? tc[(hh << 6) + w] : 0.f;
    }
    __syncthreads();
    float acc = 0.f;
#pragma unroll
    for (int j = 0; j < 13; ++j) {
      int hh = h0 + ty + j - 6;
      if ((unsigned)hh < 64u) acc = fmaf(K[j], shin[ty + j][w], acc);
    }
    shh[ty][w] = acc;
    __syncthreads();
    float o = 0.f;
#pragma unroll
    for (int j = 0; j < 13; ++j) {
      int wj = w + j - 6;
      if ((unsigned)wj < 64u) o = fmaf(K[j], shh[ty][wj], o);
    }
    int h = h0 + ty;
    vbuf[(size_t)c * NV + (d << 12) + (h << 6) + w] = o;
    fout[((size_t)(w << 12) + (h << 6) + d) * 3 + c] = o;
  }
}

// ============ MFMA helpers (tile 16x4x4, halo 18x6x6, channel-last bf16) ============
// 7-group K repack: group g = ci8 block g (ci = 8g..8g+7; 50 real, pad to 56),
// per group 7 c-iters, tap = 4c + kb (27 real of 28 slots). No ci interleave.
// LDS per buffer: 648 halo voxels x 16 B (one ci8 block) = 10368 B, padded to 12288.
// slot S = (dd*6+hh)*18 + wws; addr = S*16.
#define MFMA_PREP_G7(XB, ZP)                                                       \
  const unsigned short* gp[3];                                                     \
  _Pragma("unroll")                                                                \
  for (int k = 0; k < 3; ++k) {                                                    \
    int S = wv * 192 + k * 64 + lane;                                              \
    int wws = S % 18; int t = S / 18;                                              \
    int hh = t % 6; int dd = t / 6;                                                \
    int gz = d0 + dd - 1, gy = h0 + hh - 1, gx = w0 + wws - 1;                     \
    bool ok = (S < 648) && ((unsigned)gz < 64u) && ((unsigned)gy < 64u) && ((unsigned)gx < 64u); \
    gp[k] = ok ? ((XB) + (((gz << 12) + (gy << 6) + gx) << 6)) : (ZP);             \
  }

// async stage of ci8-group G into DSTBUF (wave wv owns slots [wv*192, wv*192+192))
#define MFMA_ISSUE7(G, DSTBUF)                                                     \
  _Pragma("unroll")                                                                \
  for (int k = 0; k < 3; ++k)                                                      \
    gld16(gp[k] + (G) * 8, (DSTBUF) + wv * 3072 + k * 1024);

// tap = 4c + kb; voxel offset (kd,kh,kw): dd stride 1728, hh stride 288, wws stride 16
#define TAP_ADDR7                                                                  \
  int tap = 4 * c + kb;                                                            \
  int tapc = min(tap, 26);                                                         \
  int kd = (tapc * 57) >> 9;                                                       \
  int rem = tapc - kd * 9;                                                         \
  int kh = (rem * 43) >> 7;                                                        \
  int kw = rem - kh * 3;                                                           \
  int rb = kd * 1728 + kh * 288 + kw * 16;

// XCD-aware bijective swizzle (nwg=1024, 128-chunk per XCD -> d-slab L2 locality)
#define MFMA_BLOCKID                                                               \
  int f = blockIdx.x + 4 * (blockIdx.y + 16 * blockIdx.z);                         \
  int nid = (f & 7) * 128 + (f >> 3);                                              \
  const int w0 = (nid & 3) * 16, h0 = ((nid >> 2) & 15) * 4, d0 = (nid >> 6) * 4;

// channel-last bf16 epilogue (m = mf*16 + kb*4 + r, n = ww)
#define MFMA_EPILOGUE(ACC, XOUT)                                                   \
  _Pragma("unroll")                                                                \
  for (int nf = 0; nf < 4; ++nf) {                                                 \
    int idx = ((d0 + wv) << 12) + ((h0 + nf) << 6) + (w0 + ww);                    \
    unsigned int base = (unsigned int)idx * 64u + kb * 4u;                         \
    _Pragma("unroll")                                                              \
    for (int mf = 0; mf < 4; ++mf) {                                               \
      float v0 = ACC[mf][nf][0], v1 = ACC[mf][nf][1];                              \
      float v2 = ACC[mf][nf][2], v3 = ACC[mf][nf][3];                              \
      v0 = (v0 >= 0.f) ? v0 : 0.01f * v0;                                          \
      v1 = (v1 >= 0.f) ? v1 : 0.01f * v1;                                          \
      v2 = (v2 >= 0.f) ? v2 : 0.01f * v2;                                          \
      v3 = (v3 >= 0.f) ? v3 : 0.01f * v3;                                          \
      unsigned int u0 = (unsigned int)f2bf(v0) | ((unsigned int)f2bf(v1) << 16);   \
      unsigned int u1 = (unsigned int)f2bf(v2) | ((unsigned int)f2bf(v3) << 16);   \
      *(uint2*)((XOUT) + base + mf * 16u) = make_uint2(u0, u1);                    \
    }                                                                              \
  }

// ---------------- conv1: MFMA implicit GEMM (3ch -> 50), K=128, tile 16x4x4 ----------------
__global__ __launch_bounds__(256) void conv1_mfma(const unsigned short* __restrict__ cinb,
                                                  const unsigned short* __restrict__ w1m,
                                                  unsigned short* __restrict__ x1b) {
  __shared__ char sh[1296 * 8];
  const int tid = threadIdx.x;
  const int lane = tid & 63;
  const int wv = tid >> 6;
  const int ww = lane & 15;
  const int kb = lane >> 4;
  MFMA_BLOCKID

  int gofs[6]; int lofs[6]; bool gok[6]; bool sval[6];
#pragma unroll
  for (int k = 0; k < 6; ++k) {
    int s = tid + k * 256;
    sval[k] = (s < 1296);
    int wws = s % 18; int rest = s / 18;
    int hh = rest % 6; int dd = rest / 6;
    int gz = d0 + dd - 1, gy = h0 + hh - 1, gx = w0 + wws - 1;
    bool ok = sval[k] && ((unsigned)gz < 64u) && ((unsigned)gy < 64u) && ((unsigned)gx < 64u);
    gok[k] = ok;
    gofs[k] = ok ? (((gz << 12) + (gy << 6) + gx) * 4) : 0;
    lofs[k] = s * 8;
  }
  {
    uint2 stg[6];
#pragma unroll
    for (int k = 0; k < 6; ++k)
      stg[k] = gok[k] ? *(const uint2*)(cinb + gofs[k]) : make_uint2(0u, 0u);
#pragma unroll
    for (int k = 0; k < 6; ++k)
      if (sval[k]) *(uint2*)(sh + lofs[k]) = stg[k];
  }
  __syncthreads();

  f32x4 acc[4][4];
#pragma unroll
  for (int mf = 0; mf < 4; ++mf)
#pragma unroll
    for (int nf = 0; nf < 4; ++nf) acc[mf][nf] = (f32x4)0.f;

#pragma unroll
  for (int g = 0; g < 4; ++g) {
    bf16x8 a0 = *(const bf16x8*)(w1m + (((g * 4 + 0) * 64 + lane) << 3));
    bf16x8 a1 = *(const bf16x8*)(w1m + (((g * 4 + 1) * 64 + lane) << 3));
    bf16x8 a2 = *(const bf16x8*)(w1m + (((g * 4 + 2) * 64 + lane) << 3));
    bf16x8 a3 = *(const bf16x8*)(w1m + (((g * 4 + 3) * 64 + lane) << 3));
    int tap0 = 8 * g + 2 * kb;
    int t0 = min(tap0, 26), t1 = min(tap0 + 1, 26);
    int kd0 = (t0 * 57) >> 9; int r0 = t0 - kd0 * 9; int kh0 = (r0 * 43) >> 7; int kw0 = r0 - kh0 * 3;
    int kd1 = (t1 * 57) >> 9; int r1 = t1 - kd1 * 9; int kh1 = (r1 * 43) >> 7; int kw1 = r1 - kh1 * 3;
#pragma unroll
    for (int nf = 0; nf < 4; ++nf) {
      union { uint2 u[2]; bf16x8 v; } bb;
      bb.u[0] = *(const uint2*)(sh + (((wv + kd0) * 6 + (nf + kh0)) * 18 + (ww + kw0)) * 8);
      bb.u[1] = *(const uint2*)(sh + (((wv + kd1) * 6 + (nf + kh1)) * 18 + (ww + kw1)) * 8);
      acc[0][nf] = __builtin_amdgcn_mfma_f32_16x16x32_bf16(a0, bb.v, acc[0][nf], 0, 0, 0);
      acc[1][nf] = __builtin_amdgcn_mfma_f32_16x16x32_bf16(a1, bb.v, acc[1][nf], 0, 0, 0);
      acc[2][nf] = __builtin_amdgcn_mfma_f32_16x16x32_bf16(a2, bb.v, acc[2][nf], 0, 0, 0);
      acc[3][nf] = __builtin_amdgcn_mfma_f32_16x16x32_bf16(a3, bb.v, acc[3][nf], 0, 0, 0);
    }
  }

  MFMA_EPILOGUE(acc, x1b)
}

// ---------------- conv2: MFMA implicit GEMM (50->50), 7-group repack, dbuf + gload_lds ----------------
__global__ __launch_bounds__(256) void conv2_mfma(const unsigned short* __restrict__ x1b,
                                                  const unsigned short* __restrict__ wtm,
                                                  unsigned short* __restrict__ x2b,
                                                  const unsigned short* __restrict__ zp) {
  __shared__ char sh[2][12288];
  const int tid = threadIdx.x;
  const int lane = tid & 63;
  const int wv = tid >> 6;
  const int ww = lane & 15;
  const int kb = lane >> 4;
  MFMA_BLOCKID

  MFMA_PREP_G7(x1b, zp)

  f32x4 acc[4][4];
#pragma unroll
  for (int mf = 0; mf < 4; ++mf)
#pragma unroll
    for (int nf = 0; nf < 4; ++nf) acc[mf][nf] = (f32x4)0.f;

  const int nb0 = wv * 1728 + ww * 16;

  MFMA_ISSUE7(0, sh[0])
  __syncthreads();

  for (int g = 0; g < 7; ++g) {
    if (g < 6) { MFMA_ISSUE7(g + 1, sh[(g + 1) & 1]) }
    const char* buf = sh[g & 1];
#pragma unroll
    for (int c = 0; c < 7; ++c) {
      bf16x8 a0 = *(const bf16x8*)(wtm + ((((g * 7 + c) * 4 + 0) * 64 + lane) << 3));
      bf16x8 a1 = *(const bf16x8*)(wtm + ((((g * 7 + c) * 4 + 1) * 64 + lane) << 3));
      bf16x8 a2 = *(const bf16x8*)(wtm + ((((g * 7 + c) * 4 + 2) * 64 + lane) << 3));
      bf16x8 a3 = *(const bf16x8*)(wtm + ((((g * 7 + c) * 4 + 3) * 64 + lane) << 3));
      TAP_ADDR7
      const char* bp = buf + nb0 + rb;
      bf16x8 b0 = *(const bf16x8*)(bp);
      bf16x8 b1 = *(const bf16x8*)(bp + 288);
      bf16x8 b2 = *(const bf16x8*)(bp + 2 * 288);
      bf16x8 b3 = *(const bf16x8*)(bp + 3 * 288);
#define MFMA_ROW(MF, AF)                                                              \
      acc[MF][0] = __builtin_amdgcn_mfma_f32_16x16x32_bf16(AF, b0, acc[MF][0], 0, 0, 0); \
      acc[MF][1] = __builtin_amdgcn_mfma_f32_16x16x32_bf16(AF, b1, acc[MF][1], 0, 0, 0); \
      acc[MF][2] = __builtin_amdgcn_mfma_f32_16x16x32_bf16(AF, b2, acc[MF][2], 0, 0, 0); \
      acc[MF][3] = __builtin_amdgcn_mfma_f32_16x16x32_bf16(AF, b3, acc[MF][3], 0, 0, 0);
      MFMA_ROW(0, a0)
      MFMA_ROW(1, a1)
      MFMA_ROW(2, a2)
      MFMA_ROW(3, a3)
#undef MFMA_ROW
    }
    if (g < 6) __syncthreads();
  }

  MFMA_EPILOGUE(acc, x2b)
}

// ---------------- conv3: MFMA (50->1, m=0 live), 7-group repack, dbuf + gload_lds ----------------
__global__ __launch_bounds__(256) void conv3_mfma(const unsigned short* __restrict__ x2b,
                                                  const unsigned short* __restrict__ w3m,
                                                  float* __restrict__ residual,
                                                  float* __restrict__ resOut,
                                                  const unsigned short* __restrict__ zp) {
  __shared__ char sh[2][12288];
  const int tid = threadIdx.x;
  const int lane = tid & 63;
  const int wv = tid >> 6;
  const int ww = lane & 15;
  const int kb = lane >> 4;
  MFMA_BLOCKID

  MFMA_PREP_G7(x2b, zp)

  f32x4 acc[4];
#pragma unroll
  for (int nf = 0; nf < 4; ++nf) acc[nf] = (f32x4)0.f;

  const int nb0 = wv * 1728 + ww * 16;

  MFMA_ISSUE7(0, sh[0])
  __syncthreads();

  for (int g = 0; g < 7; ++g) {
    if (g < 6) { MFMA_ISSUE7(g + 1, sh[(g + 1) & 1]) }
    const char* buf = sh[g & 1];
#pragma unroll
    for (int c = 0; c < 7; ++c) {
      bf16x8 a0 = *(const bf16x8*)(w3m + (((g * 7 + c) * 64 + lane) << 3));
      TAP_ADDR7
      const char* bp = buf + nb0 + rb;
      bf16x8 b0 = *(const bf16x8*)(bp);
      bf16x8 b1 = *(const bf16x8*)(bp + 288);
      bf16x8 b2 = *(const bf16x8*)(bp + 2 * 288);
      bf16x8 b3 = *(const bf16x8*)(bp + 3 * 288);
      acc[0] = __builtin_amdgcn_mfma_f32_16x16x32_bf16(a0, b0, acc[0], 0, 0, 0);
      acc[1] = __builtin_amdgcn_mfma_f32_16x16x32_bf16(a0, b1, acc[1], 0, 0, 0);
      acc[2] = __builtin_amdgcn_mfma_f32_16x16x32_bf16(a0, b2, acc[2], 0, 0, 0);
      acc[3] = __builtin_amdgcn_mfma_f32_16x16x32_bf16(a0, b3, acc[3], 0, 0, 0);
    }
    if (g < 6) __syncthreads();
  }

  if (lane < 16) {
#pragma unroll
    for (int nf = 0; nf < 4; ++nf) {
      int idx = ((d0 + wv) << 12) + ((h0 + nf) << 6) + (w0 + ww);
      float nr = residual[idx] + acc[nf][0] * 0.1f;
      residual[idx] = nr;
      resOut[idx] = nr;
    }
  }
}

// ---------------- fused res_def warp + phi warp + image update (+ cin_b pack) ----------------
__global__ void rp_fused_kernel(const float* __restrict__ rdOld, const float* __restrict__ v,
                                const float* __restrict__ residual,
                                const float* __restrict__ phiOld, float* __restrict__ phiNew,
                                const float* __restrict__ src, const float* __restrict__ seg,
                                const float* __restrict__ tgt,
                                float* __restrict__ rdNew, float* __restrict__ image,
                                unsigned short* __restrict__ cinb, int doSample) {
  int idx = blockIdx.x * 256 + threadIdx.x;
  int d = idx >> 12, h = (idx >> 6) & 63, w = idx & 63;
  const float step = 2.0f / 63.0f;
  float rres = residual[idx];

  float val = 0.f;
  if (doSample) {
    int tidx = (w << 12) + (h << 6) + d;
    float gx = (-1.f + w * step) - v[tidx] / 10.0f;
    float gy = (-1.f + h * step) - v[NV + tidx] / 10.0f;
    float gz = (-1.f + d * step) - v[2 * NV + tidx] / 10.0f;
    int id[8]; float wt[8];
    tl_make(gx, gy, gz, 1, 64, 4096, id, wt);
    val = tl_apply(rdOld, id, wt);
  }
  float nr = val + rres;
  rdNew[idx] = nr;

  float gx = (-1.f + d * step) - v[idx] / 10.0f;
  float gy = (-1.f + h * step) - v[NV + idx] / 10.0f;
  float gz = (-1.f + w * step) - v[2 * NV + idx] / 10.0f;
  int id[8]; float wt[8];
  tl_make(gx, gy, gz, 4096, 64, 1, id, wt);
  float px = tl_apply(phiOld, id, wt);
  float py = tl_apply(phiOld + NV, id, wt);
  float pz = tl_apply(phiOld + 2 * NV, id, wt);
  phiNew[idx] = px;
  phiNew[NV + idx] = py;
  phiNew[2 * NV + idx] = pz;

  int id2[8]; float wt2[8];
  tl_make(px, py, pz, 1, 64, 4096, id2, wt2);
  float sval = tl_apply(src, id2, wt2);
  float mval = tl_apply(seg, id2, wt2);
  float img = sval + nr * 4.0e-05f * mval;   // MU^2/L
  image[idx] = img;

  unsigned int u0 = (unsigned int)f2bf(rres) | ((unsigned int)f2bf(img) << 16);
  unsigned int u1 = (unsigned int)f2bf(tgt[idx]);
  *(uint2*)(cinb + (size_t)idx * 4) = make_uint2(u0, u1);
}

// ---------------- weight prep ----------------
__global__ void w1m_kernel(const float* __restrict__ W1, unsigned short* __restrict__ w1m) {
  int gid = blockIdx.x * 256 + threadIdx.x;
  if (gid >= 10 * 4 * 4 * 64 * 8) return;
  int j = gid & 7;
  int l = (gid >> 3) & 63;
  int mf = (gid >> 9) & 3;
  int g = (gid >> 11) & 3;
  int i = gid >> 13;
  int m = mf * 16 + (l & 15);
  int kb = l >> 4;
  int k = 32 * g + 8 * kb + j;
  int tap = k >> 2;
  int ci = k & 3;
  float v = 0.f;
  if (m < 50 && tap < 27 && ci < 3)
    v = W1[(((size_t)i * 50 + m) * 3 + ci) * 27 + tap];
  w1m[gid] = f2bf(v);
}

// wt2m: [i][g7][c7][mf4][lane64][j8]; ci = 8g + j, tap = 4c + kb
__global__ void wt2m_kernel(const float* __restrict__ W2, unsigned short* __restrict__ wtm) {
  int gid = blockIdx.x * 256 + threadIdx.x;
  if (gid >= 10 * 7 * 7 * 4 * 64 * 8) return;
  int j = gid & 7;
  int l = (gid >> 3) & 63;
  int mf = (gid >> 9) & 3;
  int rest = gid >> 11;
  int c = rest % 7; rest /= 7;
  int g = rest % 7; int i = rest / 7;
  int m = mf * 16 + (l & 15);
  int kb = l >> 4;
  int tap = 4 * c + kb;
  int ci = 8 * g + j;
  float v = 0.f;
  if (tap < 27 && ci < 50 && m < 50)
    v = W2[(((size_t)i * 50 + m) * 50 + ci) * 27 + tap];
  wtm[gid] = f2bf(v);
}

// w3m: [i][g7][c7][lane64][j8]; only m==0 rows nonzero
__global__ void w3m_kernel(const float* __restrict__ W3, unsigned short* __restrict__ w3m) {
  int gid = blockIdx.x * 256 + threadIdx.x;
  if (gid >= 10 * 7 * 7 * 64 * 8) return;
  int j = gid & 7;
  int l = (gid >> 3) & 63;
  int rest = gid >> 9;
  int c = rest % 7; rest /= 7;
  int g = rest % 7; int i = rest / 7;
  int m = l & 15;
  int kb = l >> 4;
  int tap = 4 * c + kb;
  int ci = 8 * g + j;
  float v = 0.f;
  if (m == 0 && tap < 27 && ci < 50)
    v = W3[((size_t)i * 50 + ci) * 27 + tap];
  w3m[gid] = f2bf(v);
}

extern "C" void kernel_launch(void* const* d_in, const int* in_sizes, int n_in,
                              void* d_out, int out_size, void* d_ws, size_t ws_size,
                              hipStream_t stream) {
  const float* src = (const float*)d_in[0];
  const float* tgt = (const float*)d_in[1];
  const float* seg = (const float*)d_in[2];
  const float* z0  = (const float*)d_in[3];
  const float* W1  = (const float*)d_in[4];
  const float* W2  = (const float*)d_in[5];
  const float* W3  = (const float*)d_in[6];
  float* out = (float*)d_out;
  float* ws = (float*)d_ws;

  const size_t N = NV;
  const size_t WT2M = (size_t)10 * 7 * 7 * 4 * 64 * 8;   // 1,003,520
  const size_t W3M  = (size_t)10 * 7 * 7 * 64 * 8;       // 250,880
  const size_t W1M  = (size_t)10 * 4 * 4 * 64 * 8;       // 81,920

  float* residual = ws;
  float* image    = ws + N;
  float* rdb[2]   = { ws + 2 * N, ws + 3 * N };
  float* phib[2]  = { ws + 4 * N, ws + 7 * N };
  float* vbuf     = ws + 10 * N;
  float* t1       = ws + 13 * N;
  unsigned short* cinb = (unsigned short*)(ws + 16 * N);
  unsigned short* x1b = (unsigned short*)(ws + 19 * N);
  unsigned short* x2b = (unsigned short*)(ws + 51 * N);
  unsigned short* wt2m = (unsigned short*)(ws + 83 * N);
  unsigned short* w3m  = wt2m + WT2M;
  unsigned short* w1m  = w3m + W3M;
  unsigned short* zp   = w1m + W1M;   // 128-B zero page

  size_t needed = 83 * N * sizeof(float) + (WT2M + W3M + W1M) * 2 + 128;
  if (ws_size < needed) return;

  float* out_image  = out;
  float* out_fields = out + N;
  float* out_grads  = out + 31 * N;
  float* out_resid  = out + 61 * N;
  float* out_rd     = out + 72 * N;

  dim3 blk(256);
  dim3 grdN((unsigned)(N / 256));
  dim3 sgrd(16, 64);
  dim3 m1grd(4, 16, 16);

  init_kernel<<<grdN, blk, 0, stream>>>(src, tgt, z0, residual, image, rdb[0], phib[0],
                                        out_resid, cinb, (float*)zp);
  w1m_kernel<<<(int)((W1M + 255) / 256), blk, 0, stream>>>(W1, w1m);
  wt2m_kernel<<<(int)((WT2M + 255) / 256), blk, 0, stream>>>(W2, wt2m);
  w3m_kernel<<<(int)((W3M + 255) / 256), blk, 0, stream>>>(W3, w3m);

  int rc = 0, pc = 0;
  for (int i = 0; i < 10; ++i) {
    gsd_kernel<<<grdN, blk, 0, stream>>>(image, residual, out_grads + (size_t)i * 3 * N, t1);
    smooth_hw<<<sgrd, blk, 0, stream>>>(t1, vbuf, out_fields + (size_t)i * 3 * N);

    conv1_mfma<<<m1grd, blk, 0, stream>>>(cinb, w1m + (size_t)i * 4 * 4 * 64 * 8, x1b);
    conv2_mfma<<<m1grd, blk, 0, stream>>>(x1b, wt2m + (size_t)i * 7 * 7 * 4 * 64 * 8, x2b, zp);
    conv3_mfma<<<m1grd, blk, 0, stream>>>(x2b, w3m + (size_t)i * 7 * 7 * 64 * 8, residual,
                                          out_resid + (size_t)(i + 1) * N, zp);

    float* rdNew = (i == 9) ? out_rd : rdb[1 - rc];
    float* imgNew = (i == 9) ? out_image : image;
    rp_fused_kernel<<<grdN, blk, 0, stream>>>(rdb[rc], vbuf, residual, phib[pc],
                                              phib[1 - pc], src, seg, tgt, rdNew, imgNew,
                                              cinb, i > 0 ? 1 : 0);
    rc = 1 - rc;
    pc = 1 - pc;
  }
}